// Round 2
// baseline (1732.673 us; speedup 1.0000x reference)
//
#include <hip/hip_runtime.h>
#include <hip/hip_bf16.h>
#include <math.h>

#define N_NODES 50000
#define N_EDGES 800000

typedef __hip_bfloat16 bf16;

__device__ __forceinline__ float b2f(bf16 v) { return __bfloat162float(v); }
__device__ __forceinline__ float lrelu(float x) { return x > 0.f ? x : 0.2f * x; }

// monotone float <-> uint encoding for atomicMax on floats
__device__ __forceinline__ unsigned enc_f(float x) {
    unsigned u = __float_as_uint(x);
    return (u & 0x80000000u) ? ~u : (u | 0x80000000u);
}
__device__ __forceinline__ float dec_f(unsigned u) {
    return (u & 0x80000000u) ? __uint_as_float(u ^ 0x80000000u)
                             : __uint_as_float(~u);
}

// ---------------------------------------------------------------------------
// Generic tiled GEMM: C[r, coff+c] = act( sum_k A[r, aoff+k] * W[c, k] + bias[c] )
// ADT: 0 = A f32, 1 = A bf16.  ODT: 0 = C f32, 1 = C bf16.
// ACT: 0 none, 1 relu, 2 sigmoid.  W is (M, K) row-major FLOAT. bias nullable.
// ---------------------------------------------------------------------------
template <int ADT, int ACT, int ODT>
__global__ __launch_bounds__(256) void gemm_kernel(
    const void* __restrict__ Av, int lda, int aoff,
    const float* __restrict__ W, const float* __restrict__ bias,
    void* __restrict__ Cv, int ldc, int coff,
    int nrows, int M, int K)
{
    const float* Af = (const float*)Av;
    const bf16*  Ab = (const bf16*)Av;
    float* Cf = (float*)Cv;
    bf16*  Cb = (bf16*)Cv;

    __shared__ float sA[16][65];
    __shared__ float sW[16][65];

    int tid  = threadIdx.x;
    int row0 = blockIdx.x * 64;
    int col0 = blockIdx.y * 64;
    int tr = tid & 15, tc = tid >> 4;

    float acc[4][4] = {};
    for (int k0 = 0; k0 < K; k0 += 16) {
#pragma unroll
        for (int i = 0; i < 4; i++) {
            int idx = tid + i * 256;
            int kk = idx & 15, r = idx >> 4;
            int grow = row0 + r, gk = k0 + kk;
            float v = 0.f;
            if (grow < nrows && gk < K)
                v = (ADT == 1) ? b2f(Ab[(size_t)grow * lda + aoff + gk])
                               : Af[(size_t)grow * lda + aoff + gk];
            sA[kk][r] = v;
        }
#pragma unroll
        for (int i = 0; i < 4; i++) {
            int idx = tid + i * 256;
            int kk = idx & 15, c = idx >> 4;
            int gcol = col0 + c, gk = k0 + kk;
            float v = 0.f;
            if (gcol < M && gk < K) v = W[(size_t)gcol * K + gk];
            sW[kk][c] = v;
        }
        __syncthreads();
#pragma unroll
        for (int kk = 0; kk < 16; kk++) {
            float a[4], w[4];
#pragma unroll
            for (int i = 0; i < 4; i++) a[i] = sA[kk][tr * 4 + i];
#pragma unroll
            for (int j = 0; j < 4; j++) w[j] = sW[kk][tc * 4 + j];
#pragma unroll
            for (int i = 0; i < 4; i++)
#pragma unroll
                for (int j = 0; j < 4; j++)
                    acc[i][j] = fmaf(a[i], w[j], acc[i][j]);
        }
        __syncthreads();
    }
#pragma unroll
    for (int i = 0; i < 4; i++) {
        int grow = row0 + tr * 4 + i;
        if (grow >= nrows) continue;
#pragma unroll
        for (int j = 0; j < 4; j++) {
            int gcol = col0 + tc * 4 + j;
            if (gcol >= M) continue;
            float v = acc[i][j];
            if (bias) v += bias[gcol];
            if (ACT == 1) v = fmaxf(v, 0.f);
            if (ACT == 2) v = 1.f / (1.f + expf(-v));
            if (ODT == 1) Cb[(size_t)grow * ldc + coff + gcol] = __float2bfloat16(v);
            else          Cf[(size_t)grow * ldc + coff + gcol] = v;
        }
    }
}

// ---------------------------------------------------------------------------
// Per-node attention scalars; also init menc with the self-loop logit.
// HDT: 0 = hw f32, 1 = hw bf16. One wave per node.
// ---------------------------------------------------------------------------
template <int HDT>
__global__ __launch_bounds__(256) void att_scores_kernel(
    const void* __restrict__ hwv, const float* __restrict__ a_src,
    const float* __restrict__ a_dst, float* __restrict__ s_src,
    float* __restrict__ s_dst, unsigned* __restrict__ menc, int n, int F)
{
    const float* hf = (const float*)hwv;
    const bf16*  hb = (const bf16*)hwv;
    int wave = threadIdx.x >> 6;
    int lane = threadIdx.x & 63;
    int node = blockIdx.x * 4 + wave;
    if (node >= n) return;
    float ps = 0.f, pd = 0.f;
    for (int f = lane; f < F; f += 64) {
        float v = (HDT == 1) ? b2f(hb[(size_t)node * F + f]) : hf[(size_t)node * F + f];
        ps = fmaf(v, a_src[f], ps);
        pd = fmaf(v, a_dst[f], pd);
    }
#pragma unroll
    for (int off = 32; off > 0; off >>= 1) {
        ps += __shfl_down(ps, off);
        pd += __shfl_down(pd, off);
    }
    if (lane == 0) {
        s_src[node] = ps;
        s_dst[node] = pd;
        menc[node] = enc_f(lrelu(ps + pd));  // self-loop logit init
    }
}

__global__ void edge_max_kernel(const int* __restrict__ src,
                                const int* __restrict__ dst,
                                const float* __restrict__ ss,
                                const float* __restrict__ sd,
                                unsigned* __restrict__ menc, int e)
{
    for (int i = blockIdx.x * blockDim.x + threadIdx.x; i < e;
         i += gridDim.x * blockDim.x) {
        int s = src[i], d = dst[i];
        float l = lrelu(ss[s] + sd[d]);
        atomicMax(menc + d, enc_f(l));
    }
}

// decode m; init denom with self-loop term
__global__ void node_mid_kernel(const float* __restrict__ ss,
                                const float* __restrict__ sd,
                                const unsigned* __restrict__ menc,
                                float* __restrict__ mfl,
                                float* __restrict__ denom, int n)
{
    int i = blockIdx.x * blockDim.x + threadIdx.x;
    if (i >= n) return;
    float m = dec_f(menc[i]);
    float self_l = lrelu(ss[i] + sd[i]);
    mfl[i] = m;
    denom[i] = expf(self_l - m);
}

__global__ void edge_sum_kernel(const int* __restrict__ src,
                                const int* __restrict__ dst,
                                const float* __restrict__ ss,
                                const float* __restrict__ sd,
                                const float* __restrict__ mfl,
                                float* __restrict__ denom, int e)
{
    for (int i = blockIdx.x * blockDim.x + threadIdx.x; i < e;
         i += gridDim.x * blockDim.x) {
        int s = src[i], d = dst[i];
        float l = lrelu(ss[s] + sd[d]);
        atomicAdd(denom + d, expf(l - mfl[d]));
    }
}

// one block per dst node, lane = feature; CSR gather + self loop; +bias, relu
template <int HDT>
__global__ void gat_gather_kernel(
    const void* __restrict__ hwv, const int* __restrict__ rowptr,
    const int* __restrict__ colidx, const float* __restrict__ ss,
    const float* __restrict__ sd, const float* __restrict__ mfl,
    const float* __restrict__ denom, const float* __restrict__ bias,
    float* __restrict__ out, int ldc, int coff, int n, int F)
{
    const float* hf = (const float*)hwv;
    const bf16*  hb = (const bf16*)hwv;
    int node = blockIdx.x;
    int f = threadIdx.x;
    float m = mfl[node];
    float sdn = sd[node];
    float inv = 1.f / (denom[node] + 1e-16f);
    float hself = (HDT == 1) ? b2f(hb[(size_t)node * F + f]) : hf[(size_t)node * F + f];
    float acc = expf(lrelu(ss[node] + sdn) - m) * inv * hself;
    int beg = rowptr[node], end = rowptr[node + 1];
    for (int e = beg; e < end; e++) {
        int s = colidx[e];
        float a = expf(lrelu(ss[s] + sdn) - m) * inv;
        float hv = (HDT == 1) ? b2f(hb[(size_t)s * F + f]) : hf[(size_t)s * F + f];
        acc = fmaf(a, hv, acc);
    }
    out[(size_t)node * ldc + coff + f] = fmaxf(acc + bias[f], 0.f);
}

// ---------------------------------------------------------------------------
// CSR build
// ---------------------------------------------------------------------------
__global__ void zero_kernel(int* __restrict__ p, int n)
{
    for (int i = blockIdx.x * blockDim.x + threadIdx.x; i < n;
         i += gridDim.x * blockDim.x)
        p[i] = 0;
}

__global__ void count_kernel(const int* __restrict__ dst, int* __restrict__ cnt,
                             int e)
{
    for (int i = blockIdx.x * blockDim.x + threadIdx.x; i < e;
         i += gridDim.x * blockDim.x)
        atomicAdd(cnt + dst[i], 1);
}

__global__ __launch_bounds__(1024) void scan_kernel(const int* __restrict__ cnt,
                                                    int* __restrict__ rowptr,
                                                    int* __restrict__ nextp,
                                                    int n)
{
    __shared__ int tmp[1024];
    int tid = threadIdx.x;
    int per = (n + 1023) / 1024;
    int lo = tid * per;
    int hi = lo + per; if (hi > n) hi = n; if (lo > n) lo = n;
    int sum = 0;
    for (int i = lo; i < hi; i++) sum += cnt[i];
    tmp[tid] = sum;
    __syncthreads();
    for (int off = 1; off < 1024; off <<= 1) {
        int v = (tid >= off) ? tmp[tid - off] : 0;
        __syncthreads();
        tmp[tid] += v;
        __syncthreads();
    }
    int run = tmp[tid] - sum;  // exclusive base
    for (int i = lo; i < hi; i++) {
        rowptr[i] = run;
        nextp[i] = run;
        run += cnt[i];
    }
    if (tid == 1023) rowptr[n] = tmp[1023];
}

__global__ void fill_kernel(const int* __restrict__ src,
                            const int* __restrict__ dst,
                            int* __restrict__ nextp, int* __restrict__ colidx,
                            int e)
{
    for (int i = blockIdx.x * blockDim.x + threadIdx.x; i < e;
         i += gridDim.x * blockDim.x) {
        int pos = atomicAdd(nextp + dst[i], 1);
        colidx[pos] = src[i];
    }
}

// ---------------------------------------------------------------------------
// LSTM cell (no h_prev; f-gate & whh dead). Writes h into out cols [64,128).
// ---------------------------------------------------------------------------
__global__ __launch_bounds__(256) void lstm_kernel(
    const float* __restrict__ x_all, const float* __restrict__ wih,
    const float* __restrict__ bih, const float* __restrict__ bhh,
    float* __restrict__ out, int n)
{
    __shared__ float w[256 * 20];
    for (int i = threadIdx.x; i < 256 * 20; i += 256) w[i] = wih[i];
    __syncthreads();
    int j = threadIdx.x & 63;
    int node = blockIdx.x * 4 + (threadIdx.x >> 6);
    if (node >= n) return;
    float t[20];
#pragma unroll
    for (int k = 0; k < 20; k++) t[k] = x_all[(size_t)node * 441 + 421 + k];
    float gi = 0.f, gg = 0.f, go = 0.f;
#pragma unroll
    for (int k = 0; k < 20; k++) {
        gi = fmaf(t[k], w[j * 20 + k], gi);
        gg = fmaf(t[k], w[(128 + j) * 20 + k], gg);
        go = fmaf(t[k], w[(192 + j) * 20 + k], go);
    }
    gi += bih[j] + bhh[j];
    gg += bih[128 + j] + bhh[128 + j];
    go += bih[192 + j] + bhh[192 + j];
    float c = (1.f / (1.f + expf(-gi))) * tanhf(gg);
    float h = (1.f / (1.f + expf(-go))) * tanhf(c);
    out[(size_t)node * 128 + 64 + j] = h;
}

// ---------------------------------------------------------------------------
extern "C" void kernel_launch(void* const* d_in, const int* in_sizes, int n_in,
                              void* d_out, int out_size, void* d_ws,
                              size_t ws_size, hipStream_t stream)
{
    const int N = N_NODES;
    const int E = N_EDGES;

    const float* x_all = (const float*)d_in[0];
    const int* edges = (const int*)d_in[1];
    const int* e_src = edges;
    const int* e_dst = edges + E;

    const float* sep1_w = (const float*)d_in[2];  const float* sep1_b = (const float*)d_in[3];
    const float* sep2_w = (const float*)d_in[4];  const float* sep2_b = (const float*)d_in[5];
    const float* sep3_w = (const float*)d_in[6];  const float* sep3_b = (const float*)d_in[7];
    const float* sep4_w = (const float*)d_in[8];  const float* sep4_b = (const float*)d_in[9];
    const float* sep5_w = (const float*)d_in[10]; const float* sep5_b = (const float*)d_in[11];
    const float* sep6_w = (const float*)d_in[12]; const float* sep6_b = (const float*)d_in[13];
    const float* sep7_w = (const float*)d_in[14]; const float* sep7_b = (const float*)d_in[15];
    const float* sep8_w = (const float*)d_in[16]; const float* sep8_b = (const float*)d_in[17];
    const float* conv1_w = (const float*)d_in[18];
    const float* conv1_as = (const float*)d_in[19];
    const float* conv1_ad = (const float*)d_in[20];
    const float* conv1_b = (const float*)d_in[21];
    const float* conv2_w = (const float*)d_in[22];
    const float* conv2_as = (const float*)d_in[23];
    const float* conv2_ad = (const float*)d_in[24];
    const float* conv2_b = (const float*)d_in[25];
    const float* conv3_w = (const float*)d_in[26];
    const float* conv3_as = (const float*)d_in[27];
    const float* conv3_ad = (const float*)d_in[28];
    const float* conv3_b = (const float*)d_in[29];
    const float* lstm_wih = (const float*)d_in[30];
    const float* lstm_bih = (const float*)d_in[32];
    const float* lstm_bhh = (const float*)d_in[33];
    const float* lin1_w = (const float*)d_in[34]; const float* lin1_b = (const float*)d_in[35];
    const float* lin2_w = (const float*)d_in[36]; const float* lin2_b = (const float*)d_in[37];
    const float* lin3_w = (const float*)d_in[38]; const float* lin3_b = (const float*)d_in[39];

    // ---- plan selection by workspace budget ----
    // plan 0: x0 f32 (102 MiB total) | plan 1: x0 bf16 (66 MiB) | plan 2: x0+hw bf16 (54 MiB)
    int plan;
    if      (ws_size >= (size_t)110 * 1000 * 1000) plan = 0;
    else if (ws_size >= (size_t)70  * 1000 * 1000) plan = 1;
    else                                           plan = 2;
    const bool xb = plan >= 1;  // x0 stored bf16
    const bool hb = plan == 2;  // hw / branch-hidden stored bf16

    char* ws = (char*)d_ws;
    size_t off = 0;
    auto alloc = [&](size_t bytes) {
        void* p = ws + off;
        off += (bytes + 255) & ~(size_t)255;
        return p;
    };
    void* x0 = alloc(xb ? (size_t)N * 384 * 2 : (size_t)N * 384 * 4);  // region reused later
    void* Bb = alloc(hb ? (size_t)N * 128 * 2 : (size_t)N * 128 * 4);  // hw / hidden
    float* ssrc  = (float*)alloc((size_t)N * 4);
    float* sdst  = (float*)alloc((size_t)N * 4);
    unsigned* menc = (unsigned*)alloc((size_t)N * 4);
    float* mfl   = (float*)alloc((size_t)N * 4);
    float* denom = (float*)alloc((size_t)N * 4);
    int* rowptr = (int*)alloc((size_t)(N + 1) * 4);
    int* nextp  = (int*)alloc((size_t)N * 4);
    int* cnt    = (int*)alloc((size_t)N * 4);
    int* colidx = (int*)alloc((size_t)E * 4);

    // aliases into the (dead-after-GAT1-gemm) x0 region; region >= 38.4 MB in all plans
    float* C    = (float*)x0;                                   // GAT ping-pong (N,128) f32
    float* xcat = (float*)x0;                                   // (N,128): GAT3 out | lstm h
    float* h1   = (float*)((char*)x0 + (size_t)N * 128 * 4);    // (N,64)
    float* h2   = (float*)x0;                                   // (N,64), xcat dead by then

    dim3 blk(256);
    auto g1 = [](int r, int c) { return dim3((unsigned)((r + 63) / 64), (unsigned)((c + 63) / 64)); };

    // --- CSR build (dst -> list of src), reused by all 3 GAT layers ---
    zero_kernel<<<256, 256, 0, stream>>>(cnt, N);
    count_kernel<<<1024, 256, 0, stream>>>(e_dst, cnt, E);
    scan_kernel<<<1, 1024, 0, stream>>>(cnt, rowptr, nextp, N);
    fill_kernel<<<1024, 256, 0, stream>>>(e_src, e_dst, nextp, colidx, E);

    // --- four MLP branches -> x0 (N,384) ---
    auto branch = [&](int aoff, int K1, int M1, const float* w1, const float* b1,
                      const float* w2, const float* b2, int M2, int coff) {
        if (hb) gemm_kernel<0, 2, 1><<<g1(N, M1), blk, 0, stream>>>(x_all, 441, aoff, w1, b1, Bb, M1, 0, N, M1, K1);
        else    gemm_kernel<0, 2, 0><<<g1(N, M1), blk, 0, stream>>>(x_all, 441, aoff, w1, b1, Bb, M1, 0, N, M1, K1);
        if (hb)      gemm_kernel<1, 1, 1><<<g1(N, M2), blk, 0, stream>>>(Bb, M1, 0, w2, b2, x0, 384, coff, N, M2, M1);
        else if (xb) gemm_kernel<0, 1, 1><<<g1(N, M2), blk, 0, stream>>>(Bb, M1, 0, w2, b2, x0, 384, coff, N, M2, M1);
        else         gemm_kernel<0, 1, 0><<<g1(N, M2), blk, 0, stream>>>(Bb, M1, 0, w2, b2, x0, 384, coff, N, M2, M1);
    };
    branch(1, 2, 64, sep1_w, sep1_b, sep5_w, sep5_b, 64, 0);
    branch(3, 13, 64, sep2_w, sep2_b, sep6_w, sep6_b, 64, 64);
    branch(16, 40, 128, sep3_w, sep3_b, sep7_w, sep7_b, 128, 128);
    branch(56, 365, 128, sep4_w, sep4_b, sep8_w, sep8_b, 128, 256);

    // --- GAT layers ---
    auto gat = [&](const void* h, int Fin, bool h_bf, const float* w, const float* as,
                   const float* ad, const float* b, float* outp, int ldc, int Fout) {
        if (h_bf) {
            if (hb) gemm_kernel<1, 0, 1><<<g1(N, Fout), blk, 0, stream>>>(h, Fin, 0, w, nullptr, Bb, Fout, 0, N, Fout, Fin);
            else    gemm_kernel<1, 0, 0><<<g1(N, Fout), blk, 0, stream>>>(h, Fin, 0, w, nullptr, Bb, Fout, 0, N, Fout, Fin);
        } else {
            if (hb) gemm_kernel<0, 0, 1><<<g1(N, Fout), blk, 0, stream>>>(h, Fin, 0, w, nullptr, Bb, Fout, 0, N, Fout, Fin);
            else    gemm_kernel<0, 0, 0><<<g1(N, Fout), blk, 0, stream>>>(h, Fin, 0, w, nullptr, Bb, Fout, 0, N, Fout, Fin);
        }
        if (hb) att_scores_kernel<1><<<(N + 3) / 4, 256, 0, stream>>>(Bb, as, ad, ssrc, sdst, menc, N, Fout);
        else    att_scores_kernel<0><<<(N + 3) / 4, 256, 0, stream>>>(Bb, as, ad, ssrc, sdst, menc, N, Fout);
        edge_max_kernel<<<1024, 256, 0, stream>>>(e_src, e_dst, ssrc, sdst, menc, E);
        node_mid_kernel<<<(N + 255) / 256, 256, 0, stream>>>(ssrc, sdst, menc, mfl, denom, N);
        edge_sum_kernel<<<1024, 256, 0, stream>>>(e_src, e_dst, ssrc, sdst, mfl, denom, E);
        if (hb) gat_gather_kernel<1><<<N, Fout, 0, stream>>>(Bb, rowptr, colidx, ssrc, sdst, mfl, denom, b, outp, ldc, 0, N, Fout);
        else    gat_gather_kernel<0><<<N, Fout, 0, stream>>>(Bb, rowptr, colidx, ssrc, sdst, mfl, denom, b, outp, ldc, 0, N, Fout);
    };
    gat(x0, 384, xb, conv1_w, conv1_as, conv1_ad, conv1_b, C, 128, 128);
    gat(C, 128, false, conv2_w, conv2_as, conv2_ad, conv2_b, C, 128, 128);
    gat(C, 128, false, conv3_w, conv3_as, conv3_ad, conv3_b, xcat, 128, 64);  // cols [0,64)

    // --- LSTM h -> xcat cols [64,128) ---
    lstm_kernel<<<(N + 3) / 4, 256, 0, stream>>>(x_all, lstm_wih, lstm_bih, lstm_bhh, xcat, N);

    // --- head ---
    gemm_kernel<0, 1, 0><<<g1(N, 64), blk, 0, stream>>>(xcat, 128, 0, lin1_w, lin1_b, h1, 64, 0, N, 64, 128);
    gemm_kernel<0, 1, 0><<<g1(N, 64), blk, 0, stream>>>(h1, 64, 0, lin2_w, lin2_b, h2, 64, 0, N, 64, 64);
    gemm_kernel<0, 0, 0><<<g1(N, 56), blk, 0, stream>>>(h2, 64, 0, lin3_w, lin3_b, d_out, 56, 0, N, 56, 64);
}

// Round 3
// 1179.202 us; speedup vs baseline: 1.4694x; 1.4694x over previous
//
#include <hip/hip_runtime.h>
#include <hip/hip_bf16.h>
#include <math.h>

#define N_NODES 50000
#define N_EDGES 800000

typedef __hip_bfloat16 bf16;
typedef __attribute__((ext_vector_type(8))) short short8;
typedef __attribute__((ext_vector_type(4))) float f32x4;

__device__ __forceinline__ float lrelu(float x) { return x > 0.f ? x : 0.2f * x; }

__device__ __forceinline__ short f2b(float v) {
    bf16 h = __float2bfloat16(v);
    return *reinterpret_cast<short*>(&h);
}
__device__ __forceinline__ float lo_bf(unsigned u) { return __uint_as_float(u << 16); }
__device__ __forceinline__ float hi_bf(unsigned u) { return __uint_as_float(u & 0xFFFF0000u); }
__device__ __forceinline__ float b2f_s(unsigned short s) {
    return __uint_as_float(((unsigned)s) << 16);
}
__device__ __forceinline__ unsigned pack_bf(float v0, float v1) {
    unsigned a = (unsigned)(unsigned short)f2b(v0);
    unsigned b = (unsigned)(unsigned short)f2b(v1);
    return a | (b << 16);
}

// ---------------------------------------------------------------------------
// MFMA GEMM: C[r, coff+c] = act( sum_k A[r, aoff+k] * W[c, k] + bias[c] )
// 64x64 tile, 256 threads = 4 waves, each wave 16 rows x 64 cols.
// ADT: 0 = A f32 (converted to bf16 in staging), 1 = A bf16.
// ODT: 0 = C f32, 1 = C bf16.  ACT: 0 none, 1 relu, 2 sigmoid.
// W is (M, K) row-major fp32 (= B^T layout), bias fp32 nullable.
// ---------------------------------------------------------------------------
template <int ADT, int ACT, int ODT>
__global__ __launch_bounds__(256) void mgemm_kernel(
    const void* __restrict__ Av, int lda, int aoff,
    const float* __restrict__ W, const float* __restrict__ bias,
    void* __restrict__ Cv, int ldc, int coff,
    int nrows, int M, int K)
{
    __shared__ short sA[64][40];  // rows padded 32 -> 40 (80B stride, 16B aligned)
    __shared__ short sB[64][40];  // sB[col][k]

    int tid = threadIdx.x;
    int row0 = blockIdx.x * 64, col0 = blockIdx.y * 64;
    int wv = tid >> 6, lane = tid & 63;
    int lrow = lane & 15, quad = lane >> 4;

    f32x4 acc[4];
#pragma unroll
    for (int ct = 0; ct < 4; ct++)
#pragma unroll
        for (int i = 0; i < 4; i++) acc[ct][i] = 0.f;

    int sr = tid >> 2;            // staging row/col 0..63
    int ks = (tid & 3) * 8;       // staging k-chunk

    for (int k0 = 0; k0 < K; k0 += 32) {
        // ---- stage A (64 rows x 32 k, bf16) ----
        {
            int grow = row0 + sr;
            short8 tmp;
            if (ADT == 0) {
                const float* Af = (const float*)Av;
#pragma unroll
                for (int j = 0; j < 8; j++) {
                    int gk = k0 + ks + j;
                    float v = (grow < nrows && gk < K)
                                  ? Af[(size_t)grow * lda + aoff + gk] : 0.f;
                    tmp[j] = f2b(v);
                }
            } else {
                const short* Ab = (const short*)Av;
                if (grow < nrows && k0 + ks + 8 <= K) {
                    tmp = *(const short8*)(Ab + (size_t)grow * lda + k0 + ks);
                } else {
#pragma unroll
                    for (int j = 0; j < 8; j++) {
                        int gk = k0 + ks + j;
                        tmp[j] = (grow < nrows && gk < K)
                                     ? Ab[(size_t)grow * lda + gk] : (short)0;
                    }
                }
            }
            *(short8*)&sA[sr][ks] = tmp;
        }
        // ---- stage B from W: sB[col][k] ----
        {
            int gcol = col0 + sr;
            short8 tmp;
#pragma unroll
            for (int j = 0; j < 8; j++) {
                int gk = k0 + ks + j;
                float v = (gcol < M && gk < K) ? W[(size_t)gcol * K + gk] : 0.f;
                tmp[j] = f2b(v);
            }
            *(short8*)&sB[sr][ks] = tmp;
        }
        __syncthreads();

        short8 a = *(short8*)&sA[wv * 16 + lrow][quad * 8];
#pragma unroll
        for (int ct = 0; ct < 4; ct++) {
            short8 b = *(short8*)&sB[ct * 16 + lrow][quad * 8];
            acc[ct] = __builtin_amdgcn_mfma_f32_16x16x32_bf16(a, b, acc[ct], 0, 0, 0);
        }
        __syncthreads();
    }

    // ---- epilogue: C/D layout col=lane&15, row=quad*4+i ----
    float* Cf = (float*)Cv;
    bf16*  Cb = (bf16*)Cv;
#pragma unroll
    for (int ct = 0; ct < 4; ct++) {
        int gcol = col0 + ct * 16 + lrow;
        if (gcol >= M) continue;
        float bv = bias ? bias[gcol] : 0.f;
#pragma unroll
        for (int i = 0; i < 4; i++) {
            int grow = row0 + wv * 16 + quad * 4 + i;
            if (grow >= nrows) continue;
            float v = acc[ct][i] + bv;
            if (ACT == 1) v = fmaxf(v, 0.f);
            if (ACT == 2) v = 1.f / (1.f + expf(-v));
            if (ODT == 1) Cb[(size_t)grow * ldc + coff + gcol] = __float2bfloat16(v);
            else          Cf[(size_t)grow * ldc + coff + gcol] = v;
        }
    }
}

// ---------------------------------------------------------------------------
// Per-node attention scalars from bf16 hw. One wave per node.
// FPL = features per lane (2 for F=128, 1 for F=64).
// ---------------------------------------------------------------------------
template <int FPL>
__global__ __launch_bounds__(256) void att_scores_kernel(
    const bf16* __restrict__ hw, const float* __restrict__ a_src,
    const float* __restrict__ a_dst, float* __restrict__ s_src,
    float* __restrict__ s_dst, int n, int F)
{
    int wv = threadIdx.x >> 6, lane = threadIdx.x & 63;
    int node = blockIdx.x * 4 + wv;
    if (node >= n) return;
    const unsigned short* hr = (const unsigned short*)(hw + (size_t)node * F);
    float ps = 0.f, pd = 0.f;
    if (FPL == 2) {
        unsigned u = *(const unsigned*)(hr + 2 * lane);
        float v0 = lo_bf(u), v1 = hi_bf(u);
        ps = v0 * a_src[2 * lane] + v1 * a_src[2 * lane + 1];
        pd = v0 * a_dst[2 * lane] + v1 * a_dst[2 * lane + 1];
    } else {
        float v = b2f_s(hr[lane]);
        ps = v * a_src[lane];
        pd = v * a_dst[lane];
    }
#pragma unroll
    for (int off = 32; off > 0; off >>= 1) {
        ps += __shfl_down(ps, off);
        pd += __shfl_down(pd, off);
    }
    if (lane == 0) {
        s_src[node] = ps;
        s_dst[node] = pd;
    }
}

// ---------------------------------------------------------------------------
// Fused GAT aggregation: one wave per dst node, single CSR pass.
// Accumulates unnormalized numerator + denominator (max-shift cancels; logits
// are O(0.1) so fp32 exp is safe), then out = relu(num/den + bias), bf16.
// ---------------------------------------------------------------------------
template <int FPL>
__global__ __launch_bounds__(256) void gat_fused_kernel(
    const bf16* __restrict__ hw, const int* __restrict__ rowptr,
    const int* __restrict__ colidx, const float* __restrict__ ss,
    const float* __restrict__ sd, const float* __restrict__ bias,
    bf16* __restrict__ out, int ldc, int coff, int n, int F)
{
    int wv = threadIdx.x >> 6, lane = threadIdx.x & 63;
    int node = blockIdx.x * 4 + wv;
    if (node >= n) return;
    const unsigned short* hwu = (const unsigned short*)hw;
    float sdn = sd[node];
    float wself = expf(lrelu(ss[node] + sdn));
    float den = wself, a0, a1 = 0.f;
    if (FPL == 2) {
        unsigned u = *(const unsigned*)(hwu + (size_t)node * F + 2 * lane);
        a0 = wself * lo_bf(u);
        a1 = wself * hi_bf(u);
    } else {
        a0 = wself * b2f_s(hwu[(size_t)node * F + lane]);
    }
    int e = rowptr[node], end = rowptr[node + 1];
    for (; e < end; e++) {
        int s = colidx[e];
        float w = expf(lrelu(ss[s] + sdn));
        den += w;
        if (FPL == 2) {
            unsigned u = *(const unsigned*)(hwu + (size_t)s * F + 2 * lane);
            a0 = fmaf(w, lo_bf(u), a0);
            a1 = fmaf(w, hi_bf(u), a1);
        } else {
            a0 = fmaf(w, b2f_s(hwu[(size_t)s * F + lane]), a0);
        }
    }
    float inv = 1.f / den;
    if (FPL == 2) {
        float v0 = fmaxf(a0 * inv + bias[2 * lane], 0.f);
        float v1 = fmaxf(a1 * inv + bias[2 * lane + 1], 0.f);
        unsigned* op = (unsigned*)(out + (size_t)node * ldc + coff);
        op[lane] = pack_bf(v0, v1);
    } else {
        out[(size_t)node * ldc + coff + lane] =
            __float2bfloat16(fmaxf(a0 * inv + bias[lane], 0.f));
    }
}

// ---------------------------------------------------------------------------
// CSR build
// ---------------------------------------------------------------------------
__global__ void zero_kernel(int* __restrict__ p, int n)
{
    for (int i = blockIdx.x * blockDim.x + threadIdx.x; i < n;
         i += gridDim.x * blockDim.x)
        p[i] = 0;
}

__global__ void count_kernel(const int* __restrict__ dst, int* __restrict__ cnt,
                             int e)
{
    for (int i = blockIdx.x * blockDim.x + threadIdx.x; i < e;
         i += gridDim.x * blockDim.x)
        atomicAdd(cnt + dst[i], 1);
}

__global__ __launch_bounds__(1024) void scan_kernel(const int* __restrict__ cnt,
                                                    int* __restrict__ rowptr,
                                                    int* __restrict__ nextp,
                                                    int n)
{
    __shared__ int tmp[1024];
    int tid = threadIdx.x;
    int per = (n + 1023) / 1024;
    int lo = tid * per;
    int hi = lo + per; if (hi > n) hi = n; if (lo > n) lo = n;
    int sum = 0;
    for (int i = lo; i < hi; i++) sum += cnt[i];
    tmp[tid] = sum;
    __syncthreads();
    for (int off = 1; off < 1024; off <<= 1) {
        int v = (tid >= off) ? tmp[tid - off] : 0;
        __syncthreads();
        tmp[tid] += v;
        __syncthreads();
    }
    int run = tmp[tid] - sum;  // exclusive base
    for (int i = lo; i < hi; i++) {
        rowptr[i] = run;
        nextp[i] = run;
        run += cnt[i];
    }
    if (tid == 1023) rowptr[n] = tmp[1023];
}

__global__ void fill_kernel(const int* __restrict__ src,
                            const int* __restrict__ dst,
                            int* __restrict__ nextp, int* __restrict__ colidx,
                            int e)
{
    for (int i = blockIdx.x * blockDim.x + threadIdx.x; i < e;
         i += gridDim.x * blockDim.x) {
        int pos = atomicAdd(nextp + dst[i], 1);
        colidx[pos] = src[i];
    }
}

// ---------------------------------------------------------------------------
// LSTM cell (no h_prev; f-gate & whh dead). Writes h bf16 into out cols [64,128).
// ---------------------------------------------------------------------------
__global__ __launch_bounds__(256) void lstm_kernel(
    const float* __restrict__ x_all, const float* __restrict__ wih,
    const float* __restrict__ bih, const float* __restrict__ bhh,
    bf16* __restrict__ out, int n)
{
    __shared__ float w[256 * 20];
    for (int i = threadIdx.x; i < 256 * 20; i += 256) w[i] = wih[i];
    __syncthreads();
    int j = threadIdx.x & 63;
    int node = blockIdx.x * 4 + (threadIdx.x >> 6);
    if (node >= n) return;
    float t[20];
#pragma unroll
    for (int k = 0; k < 20; k++) t[k] = x_all[(size_t)node * 441 + 421 + k];
    float gi = 0.f, gg = 0.f, go = 0.f;
#pragma unroll
    for (int k = 0; k < 20; k++) {
        gi = fmaf(t[k], w[j * 20 + k], gi);
        gg = fmaf(t[k], w[(128 + j) * 20 + k], gg);
        go = fmaf(t[k], w[(192 + j) * 20 + k], go);
    }
    gi += bih[j] + bhh[j];
    gg += bih[128 + j] + bhh[128 + j];
    go += bih[192 + j] + bhh[192 + j];
    float c = (1.f / (1.f + expf(-gi))) * tanhf(gg);
    float h = (1.f / (1.f + expf(-go))) * tanhf(c);
    out[(size_t)node * 128 + 64 + j] = __float2bfloat16(h);
}

// ---------------------------------------------------------------------------
extern "C" void kernel_launch(void* const* d_in, const int* in_sizes, int n_in,
                              void* d_out, int out_size, void* d_ws,
                              size_t ws_size, hipStream_t stream)
{
    const int N = N_NODES;
    const int E = N_EDGES;

    const float* x_all = (const float*)d_in[0];
    const int* edges = (const int*)d_in[1];
    const int* e_src = edges;
    const int* e_dst = edges + E;

    const float* sep1_w = (const float*)d_in[2];  const float* sep1_b = (const float*)d_in[3];
    const float* sep2_w = (const float*)d_in[4];  const float* sep2_b = (const float*)d_in[5];
    const float* sep3_w = (const float*)d_in[6];  const float* sep3_b = (const float*)d_in[7];
    const float* sep4_w = (const float*)d_in[8];  const float* sep4_b = (const float*)d_in[9];
    const float* sep5_w = (const float*)d_in[10]; const float* sep5_b = (const float*)d_in[11];
    const float* sep6_w = (const float*)d_in[12]; const float* sep6_b = (const float*)d_in[13];
    const float* sep7_w = (const float*)d_in[14]; const float* sep7_b = (const float*)d_in[15];
    const float* sep8_w = (const float*)d_in[16]; const float* sep8_b = (const float*)d_in[17];
    const float* conv1_w = (const float*)d_in[18];
    const float* conv1_as = (const float*)d_in[19];
    const float* conv1_ad = (const float*)d_in[20];
    const float* conv1_b = (const float*)d_in[21];
    const float* conv2_w = (const float*)d_in[22];
    const float* conv2_as = (const float*)d_in[23];
    const float* conv2_ad = (const float*)d_in[24];
    const float* conv2_b = (const float*)d_in[25];
    const float* conv3_w = (const float*)d_in[26];
    const float* conv3_as = (const float*)d_in[27];
    const float* conv3_ad = (const float*)d_in[28];
    const float* conv3_b = (const float*)d_in[29];
    const float* lstm_wih = (const float*)d_in[30];
    const float* lstm_bih = (const float*)d_in[32];
    const float* lstm_bhh = (const float*)d_in[33];
    const float* lin1_w = (const float*)d_in[34]; const float* lin1_b = (const float*)d_in[35];
    const float* lin2_w = (const float*)d_in[36]; const float* lin2_b = (const float*)d_in[37];
    const float* lin3_w = (const float*)d_in[38]; const float* lin3_b = (const float*)d_in[39];

    char* ws = (char*)d_ws;
    size_t off = 0;
    auto alloc = [&](size_t bytes) {
        void* p = ws + off;
        off += (bytes + 255) & ~(size_t)255;
        return p;
    };
    bf16* x0 = (bf16*)alloc((size_t)N * 384 * 2);  // region reused for C/xcat/h2
    bf16* Bb = (bf16*)alloc((size_t)N * 128 * 2);  // hw buffer / h1
    float* ssrc = (float*)alloc((size_t)N * 4);
    float* sdst = (float*)alloc((size_t)N * 4);
    int* rowptr = (int*)alloc((size_t)(N + 1) * 4);
    int* nextp  = (int*)alloc((size_t)N * 4);
    int* cnt    = (int*)alloc((size_t)N * 4);
    int* colidx = (int*)alloc((size_t)E * 4);

    bf16* C    = x0;  // GAT in/out ping (N,128) bf16; x0 dead after GAT1 gemm
    bf16* xcat = x0;  // (N,128): GAT3 out cols 0..63 | lstm h cols 64..127
    bf16* h1   = Bb;  // (N,64) after GAT3 gather (Bb dead)
    bf16* h2   = x0;  // (N,64), xcat dead by then

    dim3 blk(256);
    auto g = [](int r, int c) {
        return dim3((unsigned)((r + 63) / 64), (unsigned)((c + 63) / 64));
    };
    int nb4 = (N + 3) / 4;

    // --- CSR build (dst -> list of src), reused by all 3 GAT layers ---
    zero_kernel<<<256, 256, 0, stream>>>(cnt, N);
    count_kernel<<<1024, 256, 0, stream>>>(e_dst, cnt, E);
    scan_kernel<<<1, 1024, 0, stream>>>(cnt, rowptr, nextp, N);
    fill_kernel<<<1024, 256, 0, stream>>>(e_src, e_dst, nextp, colidx, E);

    // --- four MLP branches -> x0 (N,384) bf16 ---
    auto branch = [&](int aoff, int K1, int M1, const float* w1, const float* b1,
                      const float* w2, const float* b2, int M2, int coff) {
        mgemm_kernel<0, 2, 1><<<g(N, M1), blk, 0, stream>>>(
            x_all, 441, aoff, w1, b1, Bb, M1, 0, N, M1, K1);
        mgemm_kernel<1, 1, 1><<<g(N, M2), blk, 0, stream>>>(
            Bb, M1, 0, w2, b2, x0, 384, coff, N, M2, M1);
    };
    branch(1, 2, 64, sep1_w, sep1_b, sep5_w, sep5_b, 64, 0);
    branch(3, 13, 64, sep2_w, sep2_b, sep6_w, sep6_b, 64, 64);
    branch(16, 40, 128, sep3_w, sep3_b, sep7_w, sep7_b, 128, 128);
    branch(56, 365, 128, sep4_w, sep4_b, sep8_w, sep8_b, 128, 256);

    // --- GAT layers ---
    // GAT1: in x0 (N,384) -> hw Bb (N,128) -> out C (N,128)
    mgemm_kernel<1, 0, 1><<<g(N, 128), blk, 0, stream>>>(
        x0, 384, 0, conv1_w, nullptr, Bb, 128, 0, N, 128, 384);
    att_scores_kernel<2><<<nb4, 256, 0, stream>>>(Bb, conv1_as, conv1_ad, ssrc, sdst, N, 128);
    gat_fused_kernel<2><<<nb4, 256, 0, stream>>>(
        Bb, rowptr, colidx, ssrc, sdst, conv1_b, C, 128, 0, N, 128);

    // GAT2: in C -> hw Bb -> out C (in-place ok: gather reads only Bb)
    mgemm_kernel<1, 0, 1><<<g(N, 128), blk, 0, stream>>>(
        C, 128, 0, conv2_w, nullptr, Bb, 128, 0, N, 128, 128);
    att_scores_kernel<2><<<nb4, 256, 0, stream>>>(Bb, conv2_as, conv2_ad, ssrc, sdst, N, 128);
    gat_fused_kernel<2><<<nb4, 256, 0, stream>>>(
        Bb, rowptr, colidx, ssrc, sdst, conv2_b, C, 128, 0, N, 128);

    // GAT3: in C -> hw Bb (N,64) -> out xcat cols [0,64)
    mgemm_kernel<1, 0, 1><<<g(N, 64), blk, 0, stream>>>(
        C, 128, 0, conv3_w, nullptr, Bb, 64, 0, N, 64, 128);
    att_scores_kernel<1><<<nb4, 256, 0, stream>>>(Bb, conv3_as, conv3_ad, ssrc, sdst, N, 64);
    gat_fused_kernel<1><<<nb4, 256, 0, stream>>>(
        Bb, rowptr, colidx, ssrc, sdst, conv3_b, xcat, 128, 0, N, 64);

    // --- LSTM h -> xcat cols [64,128) ---
    lstm_kernel<<<nb4, 256, 0, stream>>>(x_all, lstm_wih, lstm_bih, lstm_bhh, xcat, N);

    // --- head ---
    mgemm_kernel<1, 1, 1><<<g(N, 64), blk, 0, stream>>>(
        xcat, 128, 0, lin1_w, lin1_b, h1, 64, 0, N, 64, 128);
    mgemm_kernel<1, 1, 1><<<g(N, 64), blk, 0, stream>>>(
        h1, 64, 0, lin2_w, lin2_b, h2, 64, 0, N, 64, 64);
    mgemm_kernel<1, 0, 0><<<g(N, 56), blk, 0, stream>>>(
        h2, 64, 0, lin3_w, lin3_b, d_out, 56, 0, N, 56, 64);
}

// Round 4
// 1062.719 us; speedup vs baseline: 1.6304x; 1.1096x over previous
//
#include <hip/hip_runtime.h>
#include <hip/hip_bf16.h>
#include <math.h>

#define N_NODES 50000
#define N_EDGES 800000

typedef __hip_bfloat16 bf16;
typedef __attribute__((ext_vector_type(8))) short short8;
typedef __attribute__((ext_vector_type(4))) float f32x4;

__device__ __forceinline__ float lrelu(float x) { return x > 0.f ? x : 0.2f * x; }

__device__ __forceinline__ short f2b(float v) {
    bf16 h = __float2bfloat16(v);
    return *reinterpret_cast<short*>(&h);
}
__device__ __forceinline__ float lo_bf(unsigned u) { return __uint_as_float(u << 16); }
__device__ __forceinline__ float hi_bf(unsigned u) { return __uint_as_float(u & 0xFFFF0000u); }
__device__ __forceinline__ float b2f_s(unsigned short s) {
    return __uint_as_float(((unsigned)s) << 16);
}
__device__ __forceinline__ unsigned pack_bf(float v0, float v1) {
    unsigned a = (unsigned)(unsigned short)f2b(v0);
    unsigned b = (unsigned)(unsigned short)f2b(v1);
    return a | (b << 16);
}

// ---------------------------------------------------------------------------
// MFMA GEMM, 64 rows x CT*16 cols per block (grid.y==1 for all uses here).
// C[r, coff+c] = act( sum_k A[r, aoff+k] * W[c, k] + bias[c] )
// ADT: 0 = A f32 (scalar staging), 1 = A bf16 (vector staging, lda mult of 8).
// ODT: 0 = C f32, 1 = C bf16.  ACT: 0 none, 1 relu, 2 sigmoid.
// W is (M, K) row-major fp32, bias fp32 nullable.
// SCORES: also emit ssrc[r] = row.a_src, sdst[r] = row.a_dst (pre-act acc).
// ---------------------------------------------------------------------------
template <int ADT, int ACT, int ODT, int CT, int SCORES>
__global__ __launch_bounds__(256) void mgemm_kernel(
    const void* __restrict__ Av, int lda, int aoff,
    const float* __restrict__ W, const float* __restrict__ bias,
    void* __restrict__ Cv, int ldc, int coff,
    int nrows, int M, int K,
    const float* __restrict__ a_src, const float* __restrict__ a_dst,
    float* __restrict__ ssrc, float* __restrict__ sdst)
{
    __shared__ short sA[64][40];
    __shared__ short sB[CT * 16][40];

    int tid = threadIdx.x;
    int row0 = blockIdx.x * 64, col0 = blockIdx.y * (CT * 16);
    int wv = tid >> 6, lane = tid & 63;
    int lrow = lane & 15, quad = lane >> 4;

    f32x4 acc[CT];
#pragma unroll
    for (int ct = 0; ct < CT; ct++)
#pragma unroll
        for (int i = 0; i < 4; i++) acc[ct][i] = 0.f;

    int sr = tid >> 2;       // staging row 0..63
    int ks = (tid & 3) * 8;  // k-chunk

    for (int k0 = 0; k0 < K; k0 += 32) {
        // ---- stage A ----
        {
            int grow = row0 + sr;
            short8 tmp;
            if (ADT == 0) {
                const float* Af = (const float*)Av;
#pragma unroll
                for (int j = 0; j < 8; j++) {
                    int gk = k0 + ks + j;
                    float v = (grow < nrows && gk < K)
                                  ? Af[(size_t)grow * lda + aoff + gk] : 0.f;
                    tmp[j] = f2b(v);
                }
            } else {
                const short* Ab = (const short*)Av;
                if (grow < nrows && k0 + ks + 8 <= K) {
                    tmp = *(const short8*)(Ab + (size_t)grow * lda + k0 + ks);
                } else {
#pragma unroll
                    for (int j = 0; j < 8; j++) {
                        int gk = k0 + ks + j;
                        tmp[j] = (grow < nrows && gk < K)
                                     ? Ab[(size_t)grow * lda + gk] : (short)0;
                    }
                }
            }
            *(short8*)&sA[sr][ks] = tmp;
        }
        // ---- stage B from W (f32 -> bf16) ----
        for (int idx = tid; idx < CT * 64; idx += 256) {
            int c = idx >> 2, kc = (idx & 3) * 8;
            int gcol = col0 + c;
            short8 tmp;
#pragma unroll
            for (int j = 0; j < 8; j++) {
                int gk = k0 + kc + j;
                float v = (gcol < M && gk < K) ? W[(size_t)gcol * K + gk] : 0.f;
                tmp[j] = f2b(v);
            }
            *(short8*)&sB[c][kc] = tmp;
        }
        __syncthreads();

        short8 a = *(short8*)&sA[wv * 16 + lrow][quad * 8];
#pragma unroll
        for (int ct = 0; ct < CT; ct++) {
            short8 b = *(short8*)&sB[ct * 16 + lrow][quad * 8];
            acc[ct] = __builtin_amdgcn_mfma_f32_16x16x32_bf16(a, b, acc[ct], 0, 0, 0);
        }
        __syncthreads();
    }

    // ---- epilogue: C/D layout col=lane&15, row=quad*4+i ----
    float* Cf = (float*)Cv;
    bf16*  Cb = (bf16*)Cv;
#pragma unroll
    for (int ct = 0; ct < CT; ct++) {
        int gcol = col0 + ct * 16 + lrow;
        if (gcol >= M) continue;
        float bv = bias ? bias[gcol] : 0.f;
#pragma unroll
        for (int i = 0; i < 4; i++) {
            int grow = row0 + wv * 16 + quad * 4 + i;
            if (grow >= nrows) continue;
            float v = acc[ct][i] + bv;
            if (ACT == 1) v = fmaxf(v, 0.f);
            if (ACT == 2) v = 1.f / (1.f + expf(-v));
            if (ODT == 1) Cb[(size_t)grow * ldc + coff + gcol] = __float2bfloat16(v);
            else          Cf[(size_t)grow * ldc + coff + gcol] = v;
        }
    }

    if (SCORES) {
        float as_c[CT], ad_c[CT];
#pragma unroll
        for (int ct = 0; ct < CT; ct++) {
            int gcol = col0 + ct * 16 + lrow;
            as_c[ct] = (gcol < M) ? a_src[gcol] : 0.f;
            ad_c[ct] = (gcol < M) ? a_dst[gcol] : 0.f;
        }
#pragma unroll
        for (int i = 0; i < 4; i++) {
            float ps = 0.f, pd = 0.f;
#pragma unroll
            for (int ct = 0; ct < CT; ct++) {
                ps = fmaf(acc[ct][i], as_c[ct], ps);
                pd = fmaf(acc[ct][i], ad_c[ct], pd);
            }
#pragma unroll
            for (int off = 8; off > 0; off >>= 1) {
                ps += __shfl_down(ps, off);
                pd += __shfl_down(pd, off);
            }
            if (lrow == 0) {
                int grow = row0 + wv * 16 + quad * 4 + i;
                if (grow < nrows) { ssrc[grow] = ps; sdst[grow] = pd; }
            }
        }
    }
}

// ---------------------------------------------------------------------------
// Pack an x_all column slice to a padded bf16 buffer (zero pad k in [K,stride)).
// ---------------------------------------------------------------------------
__global__ void pack_slice_kernel(const float* __restrict__ x,
                                  bf16* __restrict__ out, int off, int K,
                                  int stride, int n)
{
    size_t total = (size_t)n * stride;
    for (size_t i = (size_t)blockIdx.x * blockDim.x + threadIdx.x; i < total;
         i += (size_t)gridDim.x * blockDim.x) {
        int r = (int)(i / stride);
        int k = (int)(i - (size_t)r * stride);
        float v = (k < K) ? x[(size_t)r * 441 + off + k] : 0.f;
        out[i] = __float2bfloat16(v);
    }
}

// ---------------------------------------------------------------------------
// Fused GAT aggregation: one wave per dst node, single CSR pass.
// Edge weights computed 64-at-a-time data-parallel, broadcast via shfl.
// Max-shift cancels exactly in softmax; logits are O(0.1) so fp32 exp is safe.
// ---------------------------------------------------------------------------
template <int FPL>
__global__ __launch_bounds__(256) void gat_fused_kernel(
    const bf16* __restrict__ hw, const int* __restrict__ rowptr,
    const int* __restrict__ colidx, const float* __restrict__ ss,
    const float* __restrict__ sd, const float* __restrict__ bias,
    bf16* __restrict__ out, int ldc, int coff, int n, int F)
{
    int wv = threadIdx.x >> 6, lane = threadIdx.x & 63;
    int node = blockIdx.x * 4 + wv;
    if (node >= n) return;
    const unsigned short* hwu = (const unsigned short*)hw;
    float sdn = sd[node];
    float wself = expf(lrelu(ss[node] + sdn));
    float a0, a1 = 0.f;
    if (FPL == 2) {
        unsigned u = *(const unsigned*)(hwu + (size_t)node * F + 2 * lane);
        a0 = wself * lo_bf(u);
        a1 = wself * hi_bf(u);
    } else {
        a0 = wself * b2f_s(hwu[(size_t)node * F + lane]);
    }
    int e0 = rowptr[node];
    int deg = rowptr[node + 1] - e0;
    float den_l = 0.f;
    for (int c0 = 0; c0 < deg; c0 += 64) {
        int mye = c0 + lane;
        int s = 0;
        float w = 0.f;
        if (mye < deg) {
            s = colidx[e0 + mye];
            w = expf(lrelu(ss[s] + sdn));
        }
        den_l += w;
        int cnt = min(64, deg - c0);
        for (int j = 0; j < cnt; j++) {
            int sj = __shfl(s, j);
            float wj = __shfl(w, j);
            if (FPL == 2) {
                unsigned u = *(const unsigned*)(hwu + (size_t)sj * F + 2 * lane);
                a0 = fmaf(wj, lo_bf(u), a0);
                a1 = fmaf(wj, hi_bf(u), a1);
            } else {
                a0 = fmaf(wj, b2f_s(hwu[(size_t)sj * F + lane]), a0);
            }
        }
    }
#pragma unroll
    for (int off = 32; off > 0; off >>= 1) den_l += __shfl_xor(den_l, off);
    float inv = 1.f / (den_l + wself);
    if (FPL == 2) {
        float v0 = fmaxf(a0 * inv + bias[2 * lane], 0.f);
        float v1 = fmaxf(a1 * inv + bias[2 * lane + 1], 0.f);
        unsigned* op = (unsigned*)(out + (size_t)node * ldc + coff);
        op[lane] = pack_bf(v0, v1);
    } else {
        out[(size_t)node * ldc + coff + lane] =
            __float2bfloat16(fmaxf(a0 * inv + bias[lane], 0.f));
    }
}

// ---------------------------------------------------------------------------
// CSR build
// ---------------------------------------------------------------------------
__global__ void zero_kernel(int* __restrict__ p, int n)
{
    for (int i = blockIdx.x * blockDim.x + threadIdx.x; i < n;
         i += gridDim.x * blockDim.x)
        p[i] = 0;
}

__global__ void count_kernel(const int* __restrict__ dst, int* __restrict__ cnt,
                             int e)
{
    for (int i = blockIdx.x * blockDim.x + threadIdx.x; i < e;
         i += gridDim.x * blockDim.x)
        atomicAdd(cnt + dst[i], 1);
}

__global__ __launch_bounds__(1024) void scan_kernel(const int* __restrict__ cnt,
                                                    int* __restrict__ rowptr,
                                                    int* __restrict__ nextp,
                                                    int n)
{
    __shared__ int tmp[1024];
    int tid = threadIdx.x;
    int per = (n + 1023) / 1024;
    int lo = tid * per;
    int hi = lo + per; if (hi > n) hi = n; if (lo > n) lo = n;
    int sum = 0;
    for (int i = lo; i < hi; i++) sum += cnt[i];
    tmp[tid] = sum;
    __syncthreads();
    for (int off = 1; off < 1024; off <<= 1) {
        int v = (tid >= off) ? tmp[tid - off] : 0;
        __syncthreads();
        tmp[tid] += v;
        __syncthreads();
    }
    int run = tmp[tid] - sum;  // exclusive base
    for (int i = lo; i < hi; i++) {
        rowptr[i] = run;
        nextp[i] = run;
        run += cnt[i];
    }
    if (tid == 1023) rowptr[n] = tmp[1023];
}

__global__ void fill_kernel(const int* __restrict__ src,
                            const int* __restrict__ dst,
                            int* __restrict__ nextp, int* __restrict__ colidx,
                            int e)
{
    for (int i = blockIdx.x * blockDim.x + threadIdx.x; i < e;
         i += gridDim.x * blockDim.x) {
        int pos = atomicAdd(nextp + dst[i], 1);
        colidx[pos] = src[i];
    }
}

// ---------------------------------------------------------------------------
// LSTM cell (no h_prev; f-gate & whh dead). Writes h bf16 into out cols [64,128).
// ---------------------------------------------------------------------------
__global__ __launch_bounds__(256) void lstm_kernel(
    const float* __restrict__ x_all, const float* __restrict__ wih,
    const float* __restrict__ bih, const float* __restrict__ bhh,
    bf16* __restrict__ out, int n)
{
    __shared__ float w[256 * 20];
    for (int i = threadIdx.x; i < 256 * 20; i += 256) w[i] = wih[i];
    __syncthreads();
    int j = threadIdx.x & 63;
    int node = blockIdx.x * 4 + (threadIdx.x >> 6);
    if (node >= n) return;
    float t[20];
#pragma unroll
    for (int k = 0; k < 20; k++) t[k] = x_all[(size_t)node * 441 + 421 + k];
    float gi = 0.f, gg = 0.f, go = 0.f;
#pragma unroll
    for (int k = 0; k < 20; k++) {
        gi = fmaf(t[k], w[j * 20 + k], gi);
        gg = fmaf(t[k], w[(128 + j) * 20 + k], gg);
        go = fmaf(t[k], w[(192 + j) * 20 + k], go);
    }
    gi += bih[j] + bhh[j];
    gg += bih[128 + j] + bhh[128 + j];
    go += bih[192 + j] + bhh[192 + j];
    float c = (1.f / (1.f + expf(-gi))) * tanhf(gg);
    float h = (1.f / (1.f + expf(-go))) * tanhf(c);
    out[(size_t)node * 128 + 64 + j] = __float2bfloat16(h);
}

// ---------------------------------------------------------------------------
extern "C" void kernel_launch(void* const* d_in, const int* in_sizes, int n_in,
                              void* d_out, int out_size, void* d_ws,
                              size_t ws_size, hipStream_t stream)
{
    const int N = N_NODES;
    const int E = N_EDGES;

    const float* x_all = (const float*)d_in[0];
    const int* edges = (const int*)d_in[1];
    const int* e_src = edges;
    const int* e_dst = edges + E;

    const float* sep1_w = (const float*)d_in[2];  const float* sep1_b = (const float*)d_in[3];
    const float* sep2_w = (const float*)d_in[4];  const float* sep2_b = (const float*)d_in[5];
    const float* sep3_w = (const float*)d_in[6];  const float* sep3_b = (const float*)d_in[7];
    const float* sep4_w = (const float*)d_in[8];  const float* sep4_b = (const float*)d_in[9];
    const float* sep5_w = (const float*)d_in[10]; const float* sep5_b = (const float*)d_in[11];
    const float* sep6_w = (const float*)d_in[12]; const float* sep6_b = (const float*)d_in[13];
    const float* sep7_w = (const float*)d_in[14]; const float* sep7_b = (const float*)d_in[15];
    const float* sep8_w = (const float*)d_in[16]; const float* sep8_b = (const float*)d_in[17];
    const float* conv1_w = (const float*)d_in[18];
    const float* conv1_as = (const float*)d_in[19];
    const float* conv1_ad = (const float*)d_in[20];
    const float* conv1_b = (const float*)d_in[21];
    const float* conv2_w = (const float*)d_in[22];
    const float* conv2_as = (const float*)d_in[23];
    const float* conv2_ad = (const float*)d_in[24];
    const float* conv2_b = (const float*)d_in[25];
    const float* conv3_w = (const float*)d_in[26];
    const float* conv3_as = (const float*)d_in[27];
    const float* conv3_ad = (const float*)d_in[28];
    const float* conv3_b = (const float*)d_in[29];
    const float* lstm_wih = (const float*)d_in[30];
    const float* lstm_bih = (const float*)d_in[32];
    const float* lstm_bhh = (const float*)d_in[33];
    const float* lin1_w = (const float*)d_in[34]; const float* lin1_b = (const float*)d_in[35];
    const float* lin2_w = (const float*)d_in[36]; const float* lin2_b = (const float*)d_in[37];
    const float* lin3_w = (const float*)d_in[38]; const float* lin3_b = (const float*)d_in[39];

    char* ws = (char*)d_ws;
    size_t off = 0;
    auto alloc = [&](size_t bytes) {
        void* p = ws + off;
        off += (bytes + 255) & ~(size_t)255;
        return p;
    };
    bf16* x0 = (bf16*)alloc((size_t)N * 384 * 2);  // reused for C/xcat/h2
    bf16* Bb = (bf16*)alloc((size_t)N * 128 * 2);  // hw buffer / h1
    float* ssrc = (float*)alloc((size_t)N * 4);
    float* sdst = (float*)alloc((size_t)N * 4);
    int* rowptr = (int*)alloc((size_t)(N + 1) * 4);
    int* nextp  = (int*)alloc((size_t)N * 4);
    int* cnt    = (int*)alloc((size_t)N * 4);
    int* colidx = (int*)alloc((size_t)E * 4);
    size_t base = off;
    bool pack = (ws_size >= base + (size_t)N * (40 + 368) * 2 + 1024);
    bf16* xs3 = pack ? (bf16*)alloc((size_t)N * 40 * 2) : nullptr;
    bf16* xs4 = pack ? (bf16*)alloc((size_t)N * 368 * 2) : nullptr;

    bf16* C    = x0;  // GAT in/out ping (N,128) bf16; x0 dead after GAT1 gemm
    bf16* xcat = x0;  // (N,128): GAT3 out cols 0..63 | lstm h cols 64..127
    bf16* h1   = Bb;  // (N,64) after GAT3 gather (Bb dead)
    bf16* h2   = x0;  // (N,64), xcat dead by then

    dim3 blk(256);
    int gx = (N + 63) / 64;
    int nb4 = (N + 3) / 4;

    // --- CSR build (dst -> list of src), reused by all 3 GAT layers ---
    zero_kernel<<<256, 256, 0, stream>>>(cnt, N);
    count_kernel<<<1024, 256, 0, stream>>>(e_dst, cnt, E);
    scan_kernel<<<1, 1024, 0, stream>>>(cnt, rowptr, nextp, N);
    fill_kernel<<<1024, 256, 0, stream>>>(e_src, e_dst, nextp, colidx, E);

    // --- pack big x_all slices to bf16 ---
    if (pack) {
        pack_slice_kernel<<<4096, 256, 0, stream>>>(x_all, xs3, 16, 40, 40, N);
        pack_slice_kernel<<<8192, 256, 0, stream>>>(x_all, xs4, 56, 365, 368, N);
    }

    // --- four MLP branches -> x0 (N,384) bf16 ---
    // branch 1: K=2, M=64 | branch 2: K=13, M=64 (f32 A, tiny)
    mgemm_kernel<0, 2, 1, 4, 0><<<dim3(gx, 1), blk, 0, stream>>>(
        x_all, 441, 1, sep1_w, sep1_b, Bb, 64, 0, N, 64, 2, nullptr, nullptr, nullptr, nullptr);
    mgemm_kernel<1, 1, 1, 4, 0><<<dim3(gx, 1), blk, 0, stream>>>(
        Bb, 64, 0, sep5_w, sep5_b, x0, 384, 0, N, 64, 64, nullptr, nullptr, nullptr, nullptr);
    mgemm_kernel<0, 2, 1, 4, 0><<<dim3(gx, 1), blk, 0, stream>>>(
        x_all, 441, 3, sep2_w, sep2_b, Bb, 64, 0, N, 64, 13, nullptr, nullptr, nullptr, nullptr);
    mgemm_kernel<1, 1, 1, 4, 0><<<dim3(gx, 1), blk, 0, stream>>>(
        Bb, 64, 0, sep6_w, sep6_b, x0, 384, 64, N, 64, 64, nullptr, nullptr, nullptr, nullptr);
    if (pack) {
        mgemm_kernel<1, 2, 1, 8, 0><<<dim3(gx, 1), blk, 0, stream>>>(
            xs3, 40, 0, sep3_w, sep3_b, Bb, 128, 0, N, 128, 40, nullptr, nullptr, nullptr, nullptr);
    } else {
        mgemm_kernel<0, 2, 1, 8, 0><<<dim3(gx, 1), blk, 0, stream>>>(
            x_all, 441, 16, sep3_w, sep3_b, Bb, 128, 0, N, 128, 40, nullptr, nullptr, nullptr, nullptr);
    }
    mgemm_kernel<1, 1, 1, 8, 0><<<dim3(gx, 1), blk, 0, stream>>>(
        Bb, 128, 0, sep7_w, sep7_b, x0, 384, 128, N, 128, 128, nullptr, nullptr, nullptr, nullptr);
    if (pack) {
        mgemm_kernel<1, 2, 1, 8, 0><<<dim3(gx, 1), blk, 0, stream>>>(
            xs4, 368, 0, sep4_w, sep4_b, Bb, 128, 0, N, 128, 365, nullptr, nullptr, nullptr, nullptr);
    } else {
        mgemm_kernel<0, 2, 1, 8, 0><<<dim3(gx, 1), blk, 0, stream>>>(
            x_all, 441, 56, sep4_w, sep4_b, Bb, 128, 0, N, 128, 365, nullptr, nullptr, nullptr, nullptr);
    }
    mgemm_kernel<1, 1, 1, 8, 0><<<dim3(gx, 1), blk, 0, stream>>>(
        Bb, 128, 0, sep8_w, sep8_b, x0, 384, 256, N, 128, 128, nullptr, nullptr, nullptr, nullptr);

    // --- GAT layers (scores fused into GEMM epilogue) ---
    mgemm_kernel<1, 0, 1, 8, 1><<<dim3(gx, 1), blk, 0, stream>>>(
        x0, 384, 0, conv1_w, nullptr, Bb, 128, 0, N, 128, 384, conv1_as, conv1_ad, ssrc, sdst);
    gat_fused_kernel<2><<<nb4, 256, 0, stream>>>(
        Bb, rowptr, colidx, ssrc, sdst, conv1_b, C, 128, 0, N, 128);

    mgemm_kernel<1, 0, 1, 8, 1><<<dim3(gx, 1), blk, 0, stream>>>(
        C, 128, 0, conv2_w, nullptr, Bb, 128, 0, N, 128, 128, conv2_as, conv2_ad, ssrc, sdst);
    gat_fused_kernel<2><<<nb4, 256, 0, stream>>>(
        Bb, rowptr, colidx, ssrc, sdst, conv2_b, C, 128, 0, N, 128);

    mgemm_kernel<1, 0, 1, 4, 1><<<dim3(gx, 1), blk, 0, stream>>>(
        C, 128, 0, conv3_w, nullptr, Bb, 64, 0, N, 64, 128, conv3_as, conv3_ad, ssrc, sdst);
    gat_fused_kernel<1><<<nb4, 256, 0, stream>>>(
        Bb, rowptr, colidx, ssrc, sdst, conv3_b, xcat, 128, 0, N, 64);

    // --- LSTM h -> xcat cols [64,128) ---
    lstm_kernel<<<nb4, 256, 0, stream>>>(x_all, lstm_wih, lstm_bih, lstm_bhh, xcat, N);

    // --- head ---
    mgemm_kernel<1, 1, 1, 4, 0><<<dim3(gx, 1), blk, 0, stream>>>(
        xcat, 128, 0, lin1_w, lin1_b, h1, 64, 0, N, 64, 128, nullptr, nullptr, nullptr, nullptr);
    mgemm_kernel<1, 1, 1, 4, 0><<<dim3(gx, 1), blk, 0, stream>>>(
        h1, 64, 0, lin2_w, lin2_b, h2, 64, 0, N, 64, 64, nullptr, nullptr, nullptr, nullptr);
    mgemm_kernel<1, 0, 0, 4, 0><<<dim3(gx, 1), blk, 0, stream>>>(
        h2, 64, 0, lin3_w, lin3_b, d_out, 56, 0, N, 56, 64, nullptr, nullptr, nullptr, nullptr);
}

// Round 5
// 796.293 us; speedup vs baseline: 2.1759x; 1.3346x over previous
//
#include <hip/hip_runtime.h>
#include <hip/hip_bf16.h>
#include <math.h>

#define N_NODES 50000
#define N_EDGES 800000

typedef __hip_bfloat16 bf16;
typedef __attribute__((ext_vector_type(8))) short short8;
typedef __attribute__((ext_vector_type(4))) float f32x4;

__device__ __forceinline__ float lrelu(float x) { return x > 0.f ? x : 0.2f * x; }

__device__ __forceinline__ short f2b(float v) {
    bf16 h = __float2bfloat16(v);
    return *reinterpret_cast<short*>(&h);
}
__device__ __forceinline__ float lo_bf(unsigned u) { return __uint_as_float(u << 16); }
__device__ __forceinline__ float hi_bf(unsigned u) { return __uint_as_float(u & 0xFFFF0000u); }
__device__ __forceinline__ float b2f_s(unsigned short s) {
    return __uint_as_float(((unsigned)s) << 16);
}
__device__ __forceinline__ unsigned pack_bf(float v0, float v1) {
    unsigned a = (unsigned)(unsigned short)f2b(v0);
    unsigned b = (unsigned)(unsigned short)f2b(v1);
    return a | (b << 16);
}
__device__ __forceinline__ float sigm(float x) { return 1.f / (1.f + expf(-x)); }

// ---------------------------------------------------------------------------
// MFMA GEMM, 64 rows x CT*16 cols per block (grid.y==1).
// ADT: 0 = A f32 (scalar staging), 1 = A bf16 (vector staging).
// ODT: 0 = C f32, 1 = C bf16.  ACT: 0 none, 1 relu, 2 sigmoid.
// SCORES: emit ssrc/sdst (pre-activation row dot a_src/a_dst).
// ---------------------------------------------------------------------------
template <int ADT, int ACT, int ODT, int CT, int SCORES>
__global__ __launch_bounds__(256) void mgemm_kernel(
    const void* __restrict__ Av, int lda, int aoff,
    const float* __restrict__ W, const float* __restrict__ bias,
    void* __restrict__ Cv, int ldc, int coff,
    int nrows, int M, int K,
    const float* __restrict__ a_src, const float* __restrict__ a_dst,
    float* __restrict__ ssrc, float* __restrict__ sdst)
{
    __shared__ short sA[64][40];
    __shared__ short sB[CT * 16][40];

    int tid = threadIdx.x;
    int row0 = blockIdx.x * 64, col0 = 0;
    int wv = tid >> 6, lane = tid & 63;
    int lrow = lane & 15, quad = lane >> 4;

    f32x4 acc[CT];
#pragma unroll
    for (int ct = 0; ct < CT; ct++)
#pragma unroll
        for (int i = 0; i < 4; i++) acc[ct][i] = 0.f;

    int sr = tid >> 2;
    int ks = (tid & 3) * 8;

    for (int k0 = 0; k0 < K; k0 += 32) {
        {
            int grow = row0 + sr;
            short8 tmp;
            if (ADT == 0) {
                const float* Af = (const float*)Av;
#pragma unroll
                for (int j = 0; j < 8; j++) {
                    int gk = k0 + ks + j;
                    float v = (grow < nrows && gk < K)
                                  ? Af[(size_t)grow * lda + aoff + gk] : 0.f;
                    tmp[j] = f2b(v);
                }
            } else {
                const short* Ab = (const short*)Av;
                if (grow < nrows && k0 + ks + 8 <= K) {
                    tmp = *(const short8*)(Ab + (size_t)grow * lda + k0 + ks);
                } else {
#pragma unroll
                    for (int j = 0; j < 8; j++) {
                        int gk = k0 + ks + j;
                        tmp[j] = (grow < nrows && gk < K)
                                     ? Ab[(size_t)grow * lda + gk] : (short)0;
                    }
                }
            }
            *(short8*)&sA[sr][ks] = tmp;
        }
        for (int idx = tid; idx < CT * 64; idx += 256) {
            int c = idx >> 2, kc = (idx & 3) * 8;
            int gcol = col0 + c;
            short8 tmp;
#pragma unroll
            for (int j = 0; j < 8; j++) {
                int gk = k0 + kc + j;
                float v = (gcol < M && gk < K) ? W[(size_t)gcol * K + gk] : 0.f;
                tmp[j] = f2b(v);
            }
            *(short8*)&sB[c][kc] = tmp;
        }
        __syncthreads();

        short8 a = *(short8*)&sA[wv * 16 + lrow][quad * 8];
#pragma unroll
        for (int ct = 0; ct < CT; ct++) {
            short8 b = *(short8*)&sB[ct * 16 + lrow][quad * 8];
            acc[ct] = __builtin_amdgcn_mfma_f32_16x16x32_bf16(a, b, acc[ct], 0, 0, 0);
        }
        __syncthreads();
    }

    float* Cf = (float*)Cv;
    bf16*  Cb = (bf16*)Cv;
#pragma unroll
    for (int ct = 0; ct < CT; ct++) {
        int gcol = col0 + ct * 16 + lrow;
        if (gcol >= M) continue;
        float bv = bias ? bias[gcol] : 0.f;
#pragma unroll
        for (int i = 0; i < 4; i++) {
            int grow = row0 + wv * 16 + quad * 4 + i;
            if (grow >= nrows) continue;
            float v = acc[ct][i] + bv;
            if (ACT == 1) v = fmaxf(v, 0.f);
            if (ACT == 2) v = sigm(v);
            if (ODT == 1) Cb[(size_t)grow * ldc + coff + gcol] = __float2bfloat16(v);
            else          Cf[(size_t)grow * ldc + coff + gcol] = v;
        }
    }

    if (SCORES) {
        float as_c[CT], ad_c[CT];
#pragma unroll
        for (int ct = 0; ct < CT; ct++) {
            int gcol = col0 + ct * 16 + lrow;
            as_c[ct] = (gcol < M) ? a_src[gcol] : 0.f;
            ad_c[ct] = (gcol < M) ? a_dst[gcol] : 0.f;
        }
#pragma unroll
        for (int i = 0; i < 4; i++) {
            float ps = 0.f, pd = 0.f;
#pragma unroll
            for (int ct = 0; ct < CT; ct++) {
                ps = fmaf(acc[ct][i], as_c[ct], ps);
                pd = fmaf(acc[ct][i], ad_c[ct], pd);
            }
#pragma unroll
            for (int off = 8; off > 0; off >>= 1) {
                ps += __shfl_down(ps, off);
                pd += __shfl_down(pd, off);
            }
            if (lrow == 0) {
                int grow = row0 + wv * 16 + quad * 4 + i;
                if (grow < nrows) { ssrc[grow] = ps; sdst[grow] = pd; }
            }
        }
    }
}

// ---------------------------------------------------------------------------
// Fused 2-layer MLP branch: out = relu(W2 @ sig(W1 @ a + b1) + b2), bf16 out.
// 64 rows per block. M1 = CT1*16, M2 = CT2*16 exactly.
// ---------------------------------------------------------------------------
template <int ADT, int CT1, int CT2>
__global__ __launch_bounds__(256) void brmlp_kernel(
    const void* __restrict__ Av, int lda, int aoff,
    const float* __restrict__ W1, const float* __restrict__ B1,
    const float* __restrict__ W2, const float* __restrict__ B2,
    bf16* __restrict__ out, int ldc, int coff, int nrows, int K1)
{
    constexpr int CTB = (CT1 > CT2 ? CT1 : CT2);
    constexpr int M1 = CT1 * 16;
    __shared__ short sA[64][40];
    __shared__ short sB[CTB * 16][40];
    __shared__ short sH[64][M1 + 8];

    int tid = threadIdx.x;
    int row0 = blockIdx.x * 64;
    int wv = tid >> 6, lane = tid & 63;
    int lrow = lane & 15, quad = lane >> 4;
    int sr = tid >> 2, ks = (tid & 3) * 8;

    // ---- phase 1 ----
    {
        f32x4 acc[CT1];
#pragma unroll
        for (int ct = 0; ct < CT1; ct++)
#pragma unroll
            for (int i = 0; i < 4; i++) acc[ct][i] = 0.f;

        for (int k0 = 0; k0 < K1; k0 += 32) {
            {
                int grow = row0 + sr;
                short8 tmp;
                if (ADT == 0) {
                    const float* Af = (const float*)Av;
#pragma unroll
                    for (int j = 0; j < 8; j++) {
                        int gk = k0 + ks + j;
                        float v = (grow < nrows && gk < K1)
                                      ? Af[(size_t)grow * lda + aoff + gk] : 0.f;
                        tmp[j] = f2b(v);
                    }
                } else {
                    const short* Ab = (const short*)Av;
                    if (grow < nrows && k0 + ks + 8 <= K1) {
                        tmp = *(const short8*)(Ab + (size_t)grow * lda + k0 + ks);
                    } else {
#pragma unroll
                        for (int j = 0; j < 8; j++) {
                            int gk = k0 + ks + j;
                            tmp[j] = (grow < nrows && gk < K1)
                                         ? Ab[(size_t)grow * lda + gk] : (short)0;
                        }
                    }
                }
                *(short8*)&sA[sr][ks] = tmp;
            }
            for (int idx = tid; idx < CT1 * 64; idx += 256) {
                int c = idx >> 2, kc = (idx & 3) * 8;
                short8 tmp;
#pragma unroll
                for (int j = 0; j < 8; j++) {
                    int gk = k0 + kc + j;
                    float v = (gk < K1) ? W1[(size_t)c * K1 + gk] : 0.f;
                    tmp[j] = f2b(v);
                }
                *(short8*)&sB[c][kc] = tmp;
            }
            __syncthreads();
            short8 a = *(short8*)&sA[wv * 16 + lrow][quad * 8];
#pragma unroll
            for (int ct = 0; ct < CT1; ct++) {
                short8 b = *(short8*)&sB[ct * 16 + lrow][quad * 8];
                acc[ct] = __builtin_amdgcn_mfma_f32_16x16x32_bf16(a, b, acc[ct], 0, 0, 0);
            }
            __syncthreads();
        }
        // epilogue -> sH (sigmoid)
#pragma unroll
        for (int ct = 0; ct < CT1; ct++) {
            int col = ct * 16 + lrow;
            float bv = B1[col];
#pragma unroll
            for (int i = 0; i < 4; i++) {
                int r = wv * 16 + quad * 4 + i;
                sH[r][col] = f2b(sigm(acc[ct][i] + bv));
            }
        }
        __syncthreads();
    }

    // ---- phase 2 (K2 = M1) ----
    {
        f32x4 acc[CT2];
#pragma unroll
        for (int ct = 0; ct < CT2; ct++)
#pragma unroll
            for (int i = 0; i < 4; i++) acc[ct][i] = 0.f;

        for (int k0 = 0; k0 < M1; k0 += 32) {
            for (int idx = tid; idx < CT2 * 64; idx += 256) {
                int c = idx >> 2, kc = (idx & 3) * 8;
                short8 tmp;
#pragma unroll
                for (int j = 0; j < 8; j++) {
                    int gk = k0 + kc + j;
                    tmp[j] = f2b(W2[(size_t)c * M1 + gk]);
                }
                *(short8*)&sB[c][kc] = tmp;
            }
            __syncthreads();
            short8 a = *(short8*)&sH[wv * 16 + lrow][k0 + quad * 8];
#pragma unroll
            for (int ct = 0; ct < CT2; ct++) {
                short8 b = *(short8*)&sB[ct * 16 + lrow][quad * 8];
                acc[ct] = __builtin_amdgcn_mfma_f32_16x16x32_bf16(a, b, acc[ct], 0, 0, 0);
            }
            __syncthreads();
        }
#pragma unroll
        for (int ct = 0; ct < CT2; ct++) {
            int gcol = ct * 16 + lrow;
            float bv = B2[gcol];
#pragma unroll
            for (int i = 0; i < 4; i++) {
                int grow = row0 + wv * 16 + quad * 4 + i;
                if (grow >= nrows) continue;
                float v = fmaxf(acc[ct][i] + bv, 0.f);
                out[(size_t)grow * ldc + coff + gcol] = __float2bfloat16(v);
            }
        }
    }
}

// ---------------------------------------------------------------------------
// Fused head: concat(gat3_out, lstm_h) -> lin1(relu) -> lin2(relu) -> lin3.
// 64 rows per block; everything staged through LDS.
// ---------------------------------------------------------------------------
__global__ __launch_bounds__(256) void head_kernel(
    const bf16* __restrict__ xg, const float* __restrict__ x_all,
    const float* __restrict__ wih, const float* __restrict__ bih,
    const float* __restrict__ bhh,
    const float* __restrict__ w1, const float* __restrict__ b1,
    const float* __restrict__ w2, const float* __restrict__ b2,
    const float* __restrict__ w3, const float* __restrict__ b3,
    float* __restrict__ dout, int n)
{
    __shared__ short sW[20][200];   // lstm wT[k][gate*64+j], gates i,g,o
    __shared__ float sT[64][20];
    __shared__ short sX[64][136];   // concat row
    __shared__ short sB[64][40];
    __shared__ short sH2[64][72];
    __shared__ short sH3[64][72];

    int tid = threadIdx.x;
    int row0 = blockIdx.x * 64;
    int wv = tid >> 6, lane = tid & 63;
    int lrow = lane & 15, quad = lane >> 4;

    for (int i = tid; i < 20 * 192; i += 256) {
        int k = i / 192, j = i % 192;
        int gate = j >> 6, jj = j & 63;
        int srow = (gate == 0) ? jj : (gate == 1 ? 128 + jj : 192 + jj);
        sW[k][j] = f2b(wih[srow * 20 + k]);
    }
    for (int i = tid; i < 64 * 20; i += 256) {
        int r = i / 20, k = i % 20;
        int grow = row0 + r;
        sT[r][k] = (grow < n) ? x_all[(size_t)grow * 441 + 421 + k] : 0.f;
    }
    for (int i = tid; i < 64 * 8; i += 256) {
        int r = i >> 3, c8 = (i & 7) * 8;
        int grow = row0 + r;
        short8 tmp;
        if (grow < n) {
            tmp = *(const short8*)(((const short*)xg) + (size_t)grow * 64 + c8);
        } else {
#pragma unroll
            for (int j = 0; j < 8; j++) tmp[j] = 0;
        }
        *(short8*)&sX[r][c8] = tmp;
    }
    __syncthreads();

    // lstm: thread handles 16 (r,j) outputs
    for (int p = 0; p < 16; p++) {
        int idx = p * 256 + tid;
        int r = idx >> 6, j = idx & 63;
        float gi = 0.f, gg = 0.f, go = 0.f;
#pragma unroll
        for (int k = 0; k < 20; k++) {
            float t = sT[r][k];
            gi = fmaf(t, b2f_s((unsigned short)sW[k][j]), gi);
            gg = fmaf(t, b2f_s((unsigned short)sW[k][64 + j]), gg);
            go = fmaf(t, b2f_s((unsigned short)sW[k][128 + j]), go);
        }
        gi += bih[j] + bhh[j];
        gg += bih[128 + j] + bhh[128 + j];
        go += bih[192 + j] + bhh[192 + j];
        float c = sigm(gi) * tanhf(gg);
        float h = sigm(go) * tanhf(c);
        sX[r][64 + j] = f2b(h);
    }
    __syncthreads();

    f32x4 acc[4];
    // ---- lin1: 128 -> 64, relu ----
#pragma unroll
    for (int ct = 0; ct < 4; ct++)
#pragma unroll
        for (int i = 0; i < 4; i++) acc[ct][i] = 0.f;
    for (int k0 = 0; k0 < 128; k0 += 32) {
        for (int idx = tid; idx < 256; idx += 256) {
            int c = idx >> 2, kc = (idx & 3) * 8;
            short8 tmp;
#pragma unroll
            for (int j = 0; j < 8; j++) tmp[j] = f2b(w1[(size_t)c * 128 + k0 + kc + j]);
            *(short8*)&sB[c][kc] = tmp;
        }
        __syncthreads();
        short8 a = *(short8*)&sX[wv * 16 + lrow][k0 + quad * 8];
#pragma unroll
        for (int ct = 0; ct < 4; ct++) {
            short8 b = *(short8*)&sB[ct * 16 + lrow][quad * 8];
            acc[ct] = __builtin_amdgcn_mfma_f32_16x16x32_bf16(a, b, acc[ct], 0, 0, 0);
        }
        __syncthreads();
    }
#pragma unroll
    for (int ct = 0; ct < 4; ct++) {
        int col = ct * 16 + lrow;
        float bv = b1[col];
#pragma unroll
        for (int i = 0; i < 4; i++)
            sH2[wv * 16 + quad * 4 + i][col] = f2b(fmaxf(acc[ct][i] + bv, 0.f));
    }
    __syncthreads();

    // ---- lin2: 64 -> 64, relu ----
#pragma unroll
    for (int ct = 0; ct < 4; ct++)
#pragma unroll
        for (int i = 0; i < 4; i++) acc[ct][i] = 0.f;
    for (int k0 = 0; k0 < 64; k0 += 32) {
        for (int idx = tid; idx < 256; idx += 256) {
            int c = idx >> 2, kc = (idx & 3) * 8;
            short8 tmp;
#pragma unroll
            for (int j = 0; j < 8; j++) tmp[j] = f2b(w2[(size_t)c * 64 + k0 + kc + j]);
            *(short8*)&sB[c][kc] = tmp;
        }
        __syncthreads();
        short8 a = *(short8*)&sH2[wv * 16 + lrow][k0 + quad * 8];
#pragma unroll
        for (int ct = 0; ct < 4; ct++) {
            short8 b = *(short8*)&sB[ct * 16 + lrow][quad * 8];
            acc[ct] = __builtin_amdgcn_mfma_f32_16x16x32_bf16(a, b, acc[ct], 0, 0, 0);
        }
        __syncthreads();
    }
#pragma unroll
    for (int ct = 0; ct < 4; ct++) {
        int col = ct * 16 + lrow;
        float bv = b2[col];
#pragma unroll
        for (int i = 0; i < 4; i++)
            sH3[wv * 16 + quad * 4 + i][col] = f2b(fmaxf(acc[ct][i] + bv, 0.f));
    }
    __syncthreads();

    // ---- lin3: 64 -> 56 ----
#pragma unroll
    for (int ct = 0; ct < 4; ct++)
#pragma unroll
        for (int i = 0; i < 4; i++) acc[ct][i] = 0.f;
    for (int k0 = 0; k0 < 64; k0 += 32) {
        for (int idx = tid; idx < 256; idx += 256) {
            int c = idx >> 2, kc = (idx & 3) * 8;
            short8 tmp;
#pragma unroll
            for (int j = 0; j < 8; j++)
                tmp[j] = (c < 56) ? f2b(w3[(size_t)c * 64 + k0 + kc + j]) : (short)0;
            *(short8*)&sB[c][kc] = tmp;
        }
        __syncthreads();
        short8 a = *(short8*)&sH3[wv * 16 + lrow][k0 + quad * 8];
#pragma unroll
        for (int ct = 0; ct < 4; ct++) {
            short8 b = *(short8*)&sB[ct * 16 + lrow][quad * 8];
            acc[ct] = __builtin_amdgcn_mfma_f32_16x16x32_bf16(a, b, acc[ct], 0, 0, 0);
        }
        __syncthreads();
    }
#pragma unroll
    for (int ct = 0; ct < 4; ct++) {
        int gcol = ct * 16 + lrow;
        if (gcol >= 56) continue;
        float bv = b3[gcol];
#pragma unroll
        for (int i = 0; i < 4; i++) {
            int grow = row0 + wv * 16 + quad * 4 + i;
            if (grow >= n) continue;
            dout[(size_t)grow * 56 + gcol] = acc[ct][i] + bv;
        }
    }
}

// ---------------------------------------------------------------------------
// Pack an x_all column slice to bf16 (stride = S8*8, zero pad k in [K,stride)).
// ---------------------------------------------------------------------------
template <int S8>
__global__ void pack_slice_kernel(const float* __restrict__ x,
                                  bf16* __restrict__ out, int off, int K, int n)
{
    size_t total = (size_t)n * S8;
    for (size_t i = (size_t)blockIdx.x * blockDim.x + threadIdx.x; i < total;
         i += (size_t)gridDim.x * blockDim.x) {
        int r = (int)(i / S8);
        int c8 = (int)(i % S8) * 8;
        short8 tmp;
#pragma unroll
        for (int j = 0; j < 8; j++) {
            int k = c8 + j;
            tmp[j] = f2b(k < K ? x[(size_t)r * 441 + off + k] : 0.f);
        }
        *(short8*)(((short*)out) + (size_t)r * (S8 * 8) + c8) = tmp;
    }
}

// ---------------------------------------------------------------------------
// Fused GAT aggregation (single CSR pass; max-shift cancels in softmax).
// ---------------------------------------------------------------------------
template <int FPL>
__global__ __launch_bounds__(256) void gat_fused_kernel(
    const bf16* __restrict__ hw, const int* __restrict__ rowptr,
    const int* __restrict__ colidx, const float* __restrict__ ss,
    const float* __restrict__ sd, const float* __restrict__ bias,
    bf16* __restrict__ out, int ldc, int coff, int n, int F)
{
    int wv = threadIdx.x >> 6, lane = threadIdx.x & 63;
    int node = blockIdx.x * 4 + wv;
    if (node >= n) return;
    const unsigned short* hwu = (const unsigned short*)hw;
    float sdn = sd[node];
    float wself = expf(lrelu(ss[node] + sdn));
    float a0, a1 = 0.f;
    if (FPL == 2) {
        unsigned u = *(const unsigned*)(hwu + (size_t)node * F + 2 * lane);
        a0 = wself * lo_bf(u);
        a1 = wself * hi_bf(u);
    } else {
        a0 = wself * b2f_s(hwu[(size_t)node * F + lane]);
    }
    int e0 = rowptr[node];
    int deg = rowptr[node + 1] - e0;
    float den_l = 0.f;
    for (int c0 = 0; c0 < deg; c0 += 64) {
        int mye = c0 + lane;
        int s = 0;
        float w = 0.f;
        if (mye < deg) {
            s = colidx[e0 + mye];
            w = expf(lrelu(ss[s] + sdn));
        }
        den_l += w;
        int cnt = min(64, deg - c0);
        int j = 0;
        for (; j + 1 < cnt; j += 2) {
            int s0 = __shfl(s, j), s1 = __shfl(s, j + 1);
            float w0 = __shfl(w, j), w1v = __shfl(w, j + 1);
            if (FPL == 2) {
                unsigned u0 = *(const unsigned*)(hwu + (size_t)s0 * F + 2 * lane);
                unsigned u1 = *(const unsigned*)(hwu + (size_t)s1 * F + 2 * lane);
                a0 = fmaf(w0, lo_bf(u0), a0);
                a1 = fmaf(w0, hi_bf(u0), a1);
                a0 = fmaf(w1v, lo_bf(u1), a0);
                a1 = fmaf(w1v, hi_bf(u1), a1);
            } else {
                float h0 = b2f_s(hwu[(size_t)s0 * F + lane]);
                float h1 = b2f_s(hwu[(size_t)s1 * F + lane]);
                a0 = fmaf(w0, h0, a0);
                a0 = fmaf(w1v, h1, a0);
            }
        }
        if (j < cnt) {
            int s0 = __shfl(s, j);
            float w0 = __shfl(w, j);
            if (FPL == 2) {
                unsigned u0 = *(const unsigned*)(hwu + (size_t)s0 * F + 2 * lane);
                a0 = fmaf(w0, lo_bf(u0), a0);
                a1 = fmaf(w0, hi_bf(u0), a1);
            } else {
                a0 = fmaf(w0, b2f_s(hwu[(size_t)s0 * F + lane]), a0);
            }
        }
    }
#pragma unroll
    for (int off = 32; off > 0; off >>= 1) den_l += __shfl_xor(den_l, off);
    float inv = 1.f / (den_l + wself);
    if (FPL == 2) {
        float v0 = fmaxf(a0 * inv + bias[2 * lane], 0.f);
        float v1 = fmaxf(a1 * inv + bias[2 * lane + 1], 0.f);
        unsigned* op = (unsigned*)(out + (size_t)node * ldc + coff);
        op[lane] = pack_bf(v0, v1);
    } else {
        out[(size_t)node * ldc + coff + lane] =
            __float2bfloat16(fmaxf(a0 * inv + bias[lane], 0.f));
    }
}

// ---------------------------------------------------------------------------
// CSR build: count (atomic) -> 3-phase parallel scan -> fill (atomic).
// ---------------------------------------------------------------------------
__global__ void count_kernel(const int* __restrict__ dst, int* __restrict__ cnt,
                             int e)
{
    for (int i = blockIdx.x * blockDim.x + threadIdx.x; i < e;
         i += gridDim.x * blockDim.x)
        atomicAdd(cnt + dst[i], 1);
}

#define SCAN_BLOCKS 256

__global__ __launch_bounds__(256) void scan_local_kernel(
    const int* __restrict__ cnt, int* __restrict__ rowptr,
    int* __restrict__ bsum, int n, int chunk)
{
    __shared__ int tmp[256];
    int b = blockIdx.x, tid = threadIdx.x;
    int i = b * chunk + tid;
    int v = (tid < chunk && i < n) ? cnt[i] : 0;
    tmp[tid] = v;
    __syncthreads();
    for (int off = 1; off < 256; off <<= 1) {
        int t = (tid >= off) ? tmp[tid - off] : 0;
        __syncthreads();
        tmp[tid] += t;
        __syncthreads();
    }
    if (tid < chunk && i < n) rowptr[i] = tmp[tid] - v;  // local exclusive
    if (tid == 255) bsum[b] = tmp[255];
}

__global__ __launch_bounds__(256) void scan_bsums_kernel(
    int* __restrict__ bsum, int* __restrict__ rowptr, int n)
{
    __shared__ int tmp[256];
    int tid = threadIdx.x;
    int v = bsum[tid];
    tmp[tid] = v;
    __syncthreads();
    for (int off = 1; off < 256; off <<= 1) {
        int t = (tid >= off) ? tmp[tid - off] : 0;
        __syncthreads();
        tmp[tid] += t;
        __syncthreads();
    }
    bsum[tid] = tmp[tid] - v;  // exclusive
    if (tid == 255) rowptr[n] = tmp[255];
}

__global__ __launch_bounds__(256) void scan_add_kernel(
    int* __restrict__ rowptr, int* __restrict__ nextp,
    const int* __restrict__ bsum, int n, int chunk)
{
    int b = blockIdx.x, tid = threadIdx.x;
    int i = b * chunk + tid;
    if (tid < chunk && i < n) {
        int v = rowptr[i] + bsum[b];
        rowptr[i] = v;
        nextp[i] = v;
    }
}

__global__ void fill_kernel(const int* __restrict__ src,
                            const int* __restrict__ dst,
                            int* __restrict__ nextp, int* __restrict__ colidx,
                            int e)
{
    for (int i = blockIdx.x * blockDim.x + threadIdx.x; i < e;
         i += gridDim.x * blockDim.x) {
        int pos = atomicAdd(nextp + dst[i], 1);
        colidx[pos] = src[i];
    }
}

// ---------------------------------------------------------------------------
extern "C" void kernel_launch(void* const* d_in, const int* in_sizes, int n_in,
                              void* d_out, int out_size, void* d_ws,
                              size_t ws_size, hipStream_t stream)
{
    const int N = N_NODES;
    const int E = N_EDGES;

    const float* x_all = (const float*)d_in[0];
    const int* edges = (const int*)d_in[1];
    const int* e_src = edges;
    const int* e_dst = edges + E;

    const float* sep1_w = (const float*)d_in[2];  const float* sep1_b = (const float*)d_in[3];
    const float* sep2_w = (const float*)d_in[4];  const float* sep2_b = (const float*)d_in[5];
    const float* sep3_w = (const float*)d_in[6];  const float* sep3_b = (const float*)d_in[7];
    const float* sep4_w = (const float*)d_in[8];  const float* sep4_b = (const float*)d_in[9];
    const float* sep5_w = (const float*)d_in[10]; const float* sep5_b = (const float*)d_in[11];
    const float* sep6_w = (const float*)d_in[12]; const float* sep6_b = (const float*)d_in[13];
    const float* sep7_w = (const float*)d_in[14]; const float* sep7_b = (const float*)d_in[15];
    const float* sep8_w = (const float*)d_in[16]; const float* sep8_b = (const float*)d_in[17];
    const float* conv1_w = (const float*)d_in[18];
    const float* conv1_as = (const float*)d_in[19];
    const float* conv1_ad = (const float*)d_in[20];
    const float* conv1_b = (const float*)d_in[21];
    const float* conv2_w = (const float*)d_in[22];
    const float* conv2_as = (const float*)d_in[23];
    const float* conv2_ad = (const float*)d_in[24];
    const float* conv2_b = (const float*)d_in[25];
    const float* conv3_w = (const float*)d_in[26];
    const float* conv3_as = (const float*)d_in[27];
    const float* conv3_ad = (const float*)d_in[28];
    const float* conv3_b = (const float*)d_in[29];
    const float* lstm_wih = (const float*)d_in[30];
    const float* lstm_bih = (const float*)d_in[32];
    const float* lstm_bhh = (const float*)d_in[33];
    const float* lin1_w = (const float*)d_in[34]; const float* lin1_b = (const float*)d_in[35];
    const float* lin2_w = (const float*)d_in[36]; const float* lin2_b = (const float*)d_in[37];
    const float* lin3_w = (const float*)d_in[38]; const float* lin3_b = (const float*)d_in[39];

    char* ws = (char*)d_ws;
    size_t off = 0;
    auto alloc = [&](size_t bytes) {
        void* p = ws + off;
        off += (bytes + 255) & ~(size_t)255;
        return p;
    };
    bf16* x0 = (bf16*)alloc((size_t)N * 384 * 2);  // reused for C / xg
    bf16* Bb = (bf16*)alloc((size_t)N * 128 * 2);  // hw buffer
    float* ssrc = (float*)alloc((size_t)N * 4);
    float* sdst = (float*)alloc((size_t)N * 4);
    int* rowptr = (int*)alloc((size_t)(N + 1) * 4);
    int* nextp  = (int*)alloc((size_t)N * 4);
    int* cnt    = (int*)alloc((size_t)N * 4);
    int* bsum   = (int*)alloc((size_t)SCAN_BLOCKS * 4);
    int* colidx = (int*)alloc((size_t)E * 4);
    size_t base = off;
    bool pack = (ws_size >= base + (size_t)N * (40 + 368) * 2 + 1024);
    bf16* xs3 = pack ? (bf16*)alloc((size_t)N * 40 * 2) : nullptr;
    bf16* xs4 = pack ? (bf16*)alloc((size_t)N * 368 * 2) : nullptr;

    bf16* C  = x0;  // GAT ping buffer (N,128); x0 dead after conv1 gemm
    bf16* xg = x0;  // GAT3 out (N,64); C dead after conv3 gemm

    dim3 blk(256);
    int gx = (N + 63) / 64;
    int nb4 = (N + 3) / 4;
    int chunk = (N + SCAN_BLOCKS - 1) / SCAN_BLOCKS;  // 196 <= 256

    // --- CSR build ---
    hipMemsetAsync(cnt, 0, (size_t)N * 4, stream);
    count_kernel<<<1024, 256, 0, stream>>>(e_dst, cnt, E);
    scan_local_kernel<<<SCAN_BLOCKS, 256, 0, stream>>>(cnt, rowptr, bsum, N, chunk);
    scan_bsums_kernel<<<1, 256, 0, stream>>>(bsum, rowptr, N);
    scan_add_kernel<<<SCAN_BLOCKS, 256, 0, stream>>>(rowptr, nextp, bsum, N, chunk);
    fill_kernel<<<1024, 256, 0, stream>>>(e_src, e_dst, nextp, colidx, E);

    // --- pack big x_all slices to bf16 ---
    if (pack) {
        pack_slice_kernel<5><<<1024, 256, 0, stream>>>(x_all, xs3, 16, 40, N);
        pack_slice_kernel<46><<<4096, 256, 0, stream>>>(x_all, xs4, 56, 365, N);
    }

    // --- four fused MLP branches -> x0 (N,384) bf16 ---
    brmlp_kernel<0, 4, 4><<<gx, blk, 0, stream>>>(
        x_all, 441, 1, sep1_w, sep1_b, sep5_w, sep5_b, x0, 384, 0, N, 2);
    brmlp_kernel<0, 4, 4><<<gx, blk, 0, stream>>>(
        x_all, 441, 3, sep2_w, sep2_b, sep6_w, sep6_b, x0, 384, 64, N, 13);
    if (pack) {
        brmlp_kernel<1, 8, 8><<<gx, blk, 0, stream>>>(
            xs3, 40, 0, sep3_w, sep3_b, sep7_w, sep7_b, x0, 384, 128, N, 40);
        brmlp_kernel<1, 8, 8><<<gx, blk, 0, stream>>>(
            xs4, 368, 0, sep4_w, sep4_b, sep8_w, sep8_b, x0, 384, 256, N, 365);
    } else {
        brmlp_kernel<0, 8, 8><<<gx, blk, 0, stream>>>(
            x_all, 441, 16, sep3_w, sep3_b, sep7_w, sep7_b, x0, 384, 128, N, 40);
        brmlp_kernel<0, 8, 8><<<gx, blk, 0, stream>>>(
            x_all, 441, 56, sep4_w, sep4_b, sep8_w, sep8_b, x0, 384, 256, N, 365);
    }

    // --- GAT layers (scores fused into GEMM epilogue) ---
    mgemm_kernel<1, 0, 1, 8, 1><<<gx, blk, 0, stream>>>(
        x0, 384, 0, conv1_w, nullptr, Bb, 128, 0, N, 128, 384, conv1_as, conv1_ad, ssrc, sdst);
    gat_fused_kernel<2><<<nb4, 256, 0, stream>>>(
        Bb, rowptr, colidx, ssrc, sdst, conv1_b, C, 128, 0, N, 128);

    mgemm_kernel<1, 0, 1, 8, 1><<<gx, blk, 0, stream>>>(
        C, 128, 0, conv2_w, nullptr, Bb, 128, 0, N, 128, 128, conv2_as, conv2_ad, ssrc, sdst);
    gat_fused_kernel<2><<<nb4, 256, 0, stream>>>(
        Bb, rowptr, colidx, ssrc, sdst, conv2_b, C, 128, 0, N, 128);

    mgemm_kernel<1, 0, 1, 4, 1><<<gx, blk, 0, stream>>>(
        C, 128, 0, conv3_w, nullptr, Bb, 64, 0, N, 64, 128, conv3_as, conv3_ad, ssrc, sdst);
    gat_fused_kernel<1><<<nb4, 256, 0, stream>>>(
        Bb, rowptr, colidx, ssrc, sdst, conv3_b, xg, 64, 0, N, 64);

    // --- fused head: lstm + lin1 + lin2 + lin3 ---
    head_kernel<<<gx, blk, 0, stream>>>(
        xg, x_all, lstm_wih, lstm_bih, lstm_bhh,
        lin1_w, lin1_b, lin2_w, lin2_b, lin3_w, lin3_b,
        (float*)d_out, N);
}

// Round 6
// 759.736 us; speedup vs baseline: 2.2806x; 1.0481x over previous
//
#include <hip/hip_runtime.h>
#include <hip/hip_bf16.h>
#include <math.h>

#define N_NODES 50000
#define N_EDGES 800000
#define NP 50048  // N rounded up to 64

typedef __hip_bfloat16 bf16;
typedef __attribute__((ext_vector_type(8))) short short8;
typedef __attribute__((ext_vector_type(4))) float f32x4;

__device__ __forceinline__ float lrelu(float x) { return x > 0.f ? x : 0.2f * x; }

__device__ __forceinline__ short f2b(float v) {
    bf16 h = __float2bfloat16(v);
    return *reinterpret_cast<short*>(&h);
}
__device__ __forceinline__ float lo_bf(unsigned u) { return __uint_as_float(u << 16); }
__device__ __forceinline__ float hi_bf(unsigned u) { return __uint_as_float(u & 0xFFFF0000u); }
__device__ __forceinline__ float b2f_s(unsigned short s) {
    return __uint_as_float(((unsigned)s) << 16);
}
__device__ __forceinline__ unsigned pack_bf(float v0, float v1) {
    unsigned a = (unsigned)(unsigned short)f2b(v0);
    unsigned b = (unsigned)(unsigned short)f2b(v1);
    return a | (b << 16);
}
__device__ __forceinline__ float sigm(float x) { return 1.f / (1.f + expf(-x)); }

// ---------------------------------------------------------------------------
// Batched f32 -> bf16 packer. Each segment: dst (Mp x Kp) bf16, zero-padded,
// from src rows of leading-dim lda (src may be a column-slice base pointer).
// ---------------------------------------------------------------------------
struct PackDesc {
    const float* src;
    short* dst;
    int lda, M, K, Mp, Kp;
};
struct PackArgs {
    PackDesc d[16];
    unsigned long long sz[16];
    int n;
};

__global__ __launch_bounds__(256) void pack_all_kernel(PackArgs pa,
                                                       unsigned long long total)
{
    for (unsigned long long i =
             (unsigned long long)blockIdx.x * blockDim.x + threadIdx.x;
         i < total; i += (unsigned long long)gridDim.x * blockDim.x) {
        unsigned long long off = i;
        int s = 0;
        while (s < pa.n - 1 && off >= pa.sz[s]) { off -= pa.sz[s]; s++; }
        PackDesc D = pa.d[s];
        int r = (int)(off / (unsigned)D.Kp);
        int k = (int)(off % (unsigned)D.Kp);
        float v = (r < D.M && k < D.K) ? D.src[(size_t)r * D.lda + k] : 0.f;
        D.dst[(size_t)r * D.Kp + k] = f2b(v);
    }
}

// ---------------------------------------------------------------------------
// Direct-from-global MFMA GEMM: 64 rows x CT*16 cols per block, no LDS.
// A bf16 (lda mult of 8, rows padded >= grid*64). W bf16 packed (M16 x KI*32).
// ACT: 0 none, 1 relu, 2 sigmoid. ODT: 0 f32 out, 1 bf16 out.
// SCORES: emit ssrc/sdst = row-dot a_src / a_dst of the raw accumulator.
// ---------------------------------------------------------------------------
template <int ACT, int ODT, int CT, int KI, int SCORES>
__global__ __launch_bounds__(256) void dgemm_kernel(
    const short* __restrict__ A, int lda,
    const short* __restrict__ W,
    const float* __restrict__ bias,
    void* __restrict__ Cv, int ldc, int coff, int nrows, int M,
    const float* __restrict__ a_src, const float* __restrict__ a_dst,
    float* __restrict__ ssrc, float* __restrict__ sdst)
{
    constexpr int LDW = KI * 32;
    int tid = threadIdx.x;
    int row0 = blockIdx.x * 64;
    int wv = tid >> 6, lane = tid & 63;
    int lrow = lane & 15, quad = lane >> 4;

    const short* Ap = A + (size_t)(row0 + wv * 16 + lrow) * lda + quad * 8;
    const short* Wp = W + (size_t)lrow * LDW + quad * 8;

    f32x4 acc[CT];
#pragma unroll
    for (int ct = 0; ct < CT; ct++)
#pragma unroll
        for (int i = 0; i < 4; i++) acc[ct][i] = 0.f;

#pragma unroll 4
    for (int ki = 0; ki < KI; ki++) {
        short8 a = *(const short8*)(Ap + ki * 32);
#pragma unroll
        for (int ct = 0; ct < CT; ct++) {
            short8 b = *(const short8*)(Wp + (size_t)ct * 16 * LDW + ki * 32);
            acc[ct] = __builtin_amdgcn_mfma_f32_16x16x32_bf16(a, b, acc[ct], 0, 0, 0);
        }
    }

    float* Cf = (float*)Cv;
    bf16*  Cb = (bf16*)Cv;
#pragma unroll
    for (int ct = 0; ct < CT; ct++) {
        int gcol = ct * 16 + lrow;
        if (gcol >= M) continue;
        float bv = bias ? bias[gcol] : 0.f;
#pragma unroll
        for (int i = 0; i < 4; i++) {
            int grow = row0 + wv * 16 + quad * 4 + i;
            if (grow >= nrows) continue;
            float v = acc[ct][i] + bv;
            if (ACT == 1) v = fmaxf(v, 0.f);
            if (ACT == 2) v = sigm(v);
            if (ODT == 1) Cb[(size_t)grow * ldc + coff + gcol] = __float2bfloat16(v);
            else          Cf[(size_t)grow * ldc + coff + gcol] = v;
        }
    }

    if (SCORES) {
        float as_c[CT], ad_c[CT];
#pragma unroll
        for (int ct = 0; ct < CT; ct++) {
            int gcol = ct * 16 + lrow;
            as_c[ct] = (gcol < M) ? a_src[gcol] : 0.f;
            ad_c[ct] = (gcol < M) ? a_dst[gcol] : 0.f;
        }
#pragma unroll
        for (int i = 0; i < 4; i++) {
            float ps = 0.f, pd = 0.f;
#pragma unroll
            for (int ct = 0; ct < CT; ct++) {
                ps = fmaf(acc[ct][i], as_c[ct], ps);
                pd = fmaf(acc[ct][i], ad_c[ct], pd);
            }
#pragma unroll
            for (int off = 8; off > 0; off >>= 1) {
                ps += __shfl_down(ps, off);
                pd += __shfl_down(pd, off);
            }
            if (lrow == 0) {
                int grow = row0 + wv * 16 + quad * 4 + i;
                if (grow < nrows) { ssrc[grow] = ps; sdst[grow] = pd; }
            }
        }
    }
}

// ---------------------------------------------------------------------------
// Fused 2-layer MLP branch: out = relu(W2 @ sig(W1 @ a + b1) + b2), bf16 out.
// ADT 1: A bf16 packed (rows >= NP, lda = KI1*32). ADT 0: A f32 (x_all slice),
// per-lane scalar loads with bounds guards. Hidden layer per-wave in LDS
// (no barriers: each wave writes/reads only its own 16 rows).
// ---------------------------------------------------------------------------
template <int ADT, int CT1, int CT2, int KI1>
__global__ __launch_bounds__(256) void brmlp_kernel(
    const void* __restrict__ Av, int lda, int aoff,
    const short* __restrict__ W1p, const float* __restrict__ B1,
    const short* __restrict__ W2p, const float* __restrict__ B2,
    bf16* __restrict__ out, int ldc, int coff, int nrows, int K1)
{
    constexpr int M1 = CT1 * 16;
    constexpr int LDH = M1 + 8;
    constexpr int LDW1 = KI1 * 32;
    __shared__ short sH[64][LDH];

    int tid = threadIdx.x;
    int row0 = blockIdx.x * 64;
    int wv = tid >> 6, lane = tid & 63;
    int lrow = lane & 15, quad = lane >> 4;
    int arow = row0 + wv * 16 + lrow;

    // ---- phase 1 ----
    {
        f32x4 acc[CT1];
#pragma unroll
        for (int ct = 0; ct < CT1; ct++)
#pragma unroll
            for (int i = 0; i < 4; i++) acc[ct][i] = 0.f;

#pragma unroll
        for (int ki = 0; ki < KI1; ki++) {
            short8 a;
            if (ADT == 1) {
                a = *(const short8*)((const short*)Av + (size_t)arow * lda +
                                     ki * 32 + quad * 8);
            } else {
                const float* Af = (const float*)Av;
                bool rok = arow < nrows;
#pragma unroll
                for (int j = 0; j < 8; j++) {
                    int k = ki * 32 + quad * 8 + j;
                    a[j] = (rok && k < K1)
                               ? f2b(Af[(size_t)arow * lda + aoff + k])
                               : (short)0;
                }
            }
#pragma unroll
            for (int ct = 0; ct < CT1; ct++) {
                short8 b = *(const short8*)(W1p + (size_t)(ct * 16 + lrow) * LDW1 +
                                            ki * 32 + quad * 8);
                acc[ct] = __builtin_amdgcn_mfma_f32_16x16x32_bf16(a, b, acc[ct], 0, 0, 0);
            }
        }
#pragma unroll
        for (int ct = 0; ct < CT1; ct++) {
            int col = ct * 16 + lrow;
            float bv = B1[col];
#pragma unroll
            for (int i = 0; i < 4; i++)
                sH[wv * 16 + quad * 4 + i][col] = f2b(sigm(acc[ct][i] + bv));
        }
    }

    // ---- phase 2 (K2 = M1) ----
    {
        f32x4 acc[CT2];
#pragma unroll
        for (int ct = 0; ct < CT2; ct++)
#pragma unroll
            for (int i = 0; i < 4; i++) acc[ct][i] = 0.f;

#pragma unroll
        for (int ki = 0; ki < M1 / 32; ki++) {
            short8 a = *(short8*)&sH[wv * 16 + lrow][ki * 32 + quad * 8];
#pragma unroll
            for (int ct = 0; ct < CT2; ct++) {
                short8 b = *(const short8*)(W2p + (size_t)(ct * 16 + lrow) * M1 +
                                            ki * 32 + quad * 8);
                acc[ct] = __builtin_amdgcn_mfma_f32_16x16x32_bf16(a, b, acc[ct], 0, 0, 0);
            }
        }
#pragma unroll
        for (int ct = 0; ct < CT2; ct++) {
            int gcol = ct * 16 + lrow;
            float bv = B2[gcol];
#pragma unroll
            for (int i = 0; i < 4; i++) {
                int grow = row0 + wv * 16 + quad * 4 + i;
                if (grow >= nrows) continue;
                float v = fmaxf(acc[ct][i] + bv, 0.f);
                out[(size_t)grow * ldc + coff + gcol] = __float2bfloat16(v);
            }
        }
    }
}

// ---------------------------------------------------------------------------
// Fused head: concat(gat3_out, lstm_h) -> lin1(relu) -> lin2(relu) -> lin3.
// Weights pre-packed bf16 (lin3 padded to 64 rows). Direct B-frag loads.
// ---------------------------------------------------------------------------
__global__ __launch_bounds__(256) void head_kernel(
    const bf16* __restrict__ xg, const float* __restrict__ x_all,
    const float* __restrict__ wih, const float* __restrict__ bih,
    const float* __restrict__ bhh,
    const short* __restrict__ w1p, const float* __restrict__ b1,
    const short* __restrict__ w2p, const float* __restrict__ b2,
    const short* __restrict__ w3p, const float* __restrict__ b3,
    float* __restrict__ dout, int n)
{
    __shared__ short sW[20][200];  // lstm wT[k][gate*64+j], gates i,g,o
    __shared__ float sT[64][20];
    __shared__ short sX[64][136];  // concat row (stride 272B, 16B mult)
    __shared__ short sH2[64][72];
    __shared__ short sH3[64][72];

    int tid = threadIdx.x;
    int row0 = blockIdx.x * 64;
    int wv = tid >> 6, lane = tid & 63;
    int lrow = lane & 15, quad = lane >> 4;

    for (int i = tid; i < 20 * 192; i += 256) {
        int k = i / 192, j = i % 192;
        int gate = j >> 6, jj = j & 63;
        int srow = (gate == 0) ? jj : (gate == 1 ? 128 + jj : 192 + jj);
        sW[k][j] = f2b(wih[srow * 20 + k]);
    }
    for (int i = tid; i < 64 * 20; i += 256) {
        int r = i / 20, k = i % 20;
        int grow = row0 + r;
        sT[r][k] = (grow < n) ? x_all[(size_t)grow * 441 + 421 + k] : 0.f;
    }
    for (int i = tid; i < 64 * 8; i += 256) {
        int r = i >> 3, c8 = (i & 7) * 8;
        int grow = row0 + r;
        short8 tmp;
        if (grow < n) {
            tmp = *(const short8*)(((const short*)xg) + (size_t)grow * 64 + c8);
        } else {
#pragma unroll
            for (int j = 0; j < 8; j++) tmp[j] = 0;
        }
        *(short8*)&sX[r][c8] = tmp;
    }
    __syncthreads();

    for (int p = 0; p < 16; p++) {
        int idx = p * 256 + tid;
        int r = idx >> 6, j = idx & 63;
        float gi = 0.f, gg = 0.f, go = 0.f;
#pragma unroll
        for (int k = 0; k < 20; k++) {
            float t = sT[r][k];
            gi = fmaf(t, b2f_s((unsigned short)sW[k][j]), gi);
            gg = fmaf(t, b2f_s((unsigned short)sW[k][64 + j]), gg);
            go = fmaf(t, b2f_s((unsigned short)sW[k][128 + j]), go);
        }
        gi += bih[j] + bhh[j];
        gg += bih[128 + j] + bhh[128 + j];
        go += bih[192 + j] + bhh[192 + j];
        float c = sigm(gi) * tanhf(gg);
        float h = sigm(go) * tanhf(c);
        sX[r][64 + j] = f2b(h);
    }
    __syncthreads();

    f32x4 acc[4];
    // ---- lin1: 128 -> 64, relu ----
#pragma unroll
    for (int ct = 0; ct < 4; ct++)
#pragma unroll
        for (int i = 0; i < 4; i++) acc[ct][i] = 0.f;
#pragma unroll
    for (int ki = 0; ki < 4; ki++) {
        short8 a = *(short8*)&sX[wv * 16 + lrow][ki * 32 + quad * 8];
#pragma unroll
        for (int ct = 0; ct < 4; ct++) {
            short8 b = *(const short8*)(w1p + (size_t)(ct * 16 + lrow) * 128 +
                                        ki * 32 + quad * 8);
            acc[ct] = __builtin_amdgcn_mfma_f32_16x16x32_bf16(a, b, acc[ct], 0, 0, 0);
        }
    }
#pragma unroll
    for (int ct = 0; ct < 4; ct++) {
        int col = ct * 16 + lrow;
        float bv = b1[col];
#pragma unroll
        for (int i = 0; i < 4; i++)
            sH2[wv * 16 + quad * 4 + i][col] = f2b(fmaxf(acc[ct][i] + bv, 0.f));
    }

    // ---- lin2: 64 -> 64, relu (per-wave rows; no barrier needed) ----
#pragma unroll
    for (int ct = 0; ct < 4; ct++)
#pragma unroll
        for (int i = 0; i < 4; i++) acc[ct][i] = 0.f;
#pragma unroll
    for (int ki = 0; ki < 2; ki++) {
        short8 a = *(short8*)&sH2[wv * 16 + lrow][ki * 32 + quad * 8];
#pragma unroll
        for (int ct = 0; ct < 4; ct++) {
            short8 b = *(const short8*)(w2p + (size_t)(ct * 16 + lrow) * 64 +
                                        ki * 32 + quad * 8);
            acc[ct] = __builtin_amdgcn_mfma_f32_16x16x32_bf16(a, b, acc[ct], 0, 0, 0);
        }
    }
#pragma unroll
    for (int ct = 0; ct < 4; ct++) {
        int col = ct * 16 + lrow;
        float bv = b2[col];
#pragma unroll
        for (int i = 0; i < 4; i++)
            sH3[wv * 16 + quad * 4 + i][col] = f2b(fmaxf(acc[ct][i] + bv, 0.f));
    }

    // ---- lin3: 64 -> 56 ----
#pragma unroll
    for (int ct = 0; ct < 4; ct++)
#pragma unroll
        for (int i = 0; i < 4; i++) acc[ct][i] = 0.f;
#pragma unroll
    for (int ki = 0; ki < 2; ki++) {
        short8 a = *(short8*)&sH3[wv * 16 + lrow][ki * 32 + quad * 8];
#pragma unroll
        for (int ct = 0; ct < 4; ct++) {
            short8 b = *(const short8*)(w3p + (size_t)(ct * 16 + lrow) * 64 +
                                        ki * 32 + quad * 8);
            acc[ct] = __builtin_amdgcn_mfma_f32_16x16x32_bf16(a, b, acc[ct], 0, 0, 0);
        }
    }
#pragma unroll
    for (int ct = 0; ct < 4; ct++) {
        int gcol = ct * 16 + lrow;
        if (gcol >= 56) continue;
        float bv = b3[gcol];
#pragma unroll
        for (int i = 0; i < 4; i++) {
            int grow = row0 + wv * 16 + quad * 4 + i;
            if (grow >= n) continue;
            dout[(size_t)grow * 56 + gcol] = acc[ct][i] + bv;
        }
    }
}

// ---------------------------------------------------------------------------
// Fused GAT aggregation (single CSR pass; max-shift cancels in softmax).
// ---------------------------------------------------------------------------
template <int FPL>
__global__ __launch_bounds__(256) void gat_fused_kernel(
    const bf16* __restrict__ hw, const int* __restrict__ rowptr,
    const int* __restrict__ colidx, const float* __restrict__ ss,
    const float* __restrict__ sd, const float* __restrict__ bias,
    bf16* __restrict__ out, int ldc, int coff, int n, int F)
{
    int wv = threadIdx.x >> 6, lane = threadIdx.x & 63;
    int node = blockIdx.x * 4 + wv;
    if (node >= n) return;
    const unsigned short* hwu = (const unsigned short*)hw;
    float sdn = sd[node];
    float wself = expf(lrelu(ss[node] + sdn));
    float a0, a1 = 0.f;
    if (FPL == 2) {
        unsigned u = *(const unsigned*)(hwu + (size_t)node * F + 2 * lane);
        a0 = wself * lo_bf(u);
        a1 = wself * hi_bf(u);
    } else {
        a0 = wself * b2f_s(hwu[(size_t)node * F + lane]);
    }
    int e0 = rowptr[node];
    int deg = rowptr[node + 1] - e0;
    float den_l = 0.f;
    for (int c0 = 0; c0 < deg; c0 += 64) {
        int mye = c0 + lane;
        int s = 0;
        float w = 0.f;
        if (mye < deg) {
            s = colidx[e0 + mye];
            w = expf(lrelu(ss[s] + sdn));
        }
        den_l += w;
        int cnt = min(64, deg - c0);
        int j = 0;
        for (; j + 1 < cnt; j += 2) {
            int s0 = __shfl(s, j), s1 = __shfl(s, j + 1);
            float w0 = __shfl(w, j), w1v = __shfl(w, j + 1);
            if (FPL == 2) {
                unsigned u0 = *(const unsigned*)(hwu + (size_t)s0 * F + 2 * lane);
                unsigned u1 = *(const unsigned*)(hwu + (size_t)s1 * F + 2 * lane);
                a0 = fmaf(w0, lo_bf(u0), a0);
                a1 = fmaf(w0, hi_bf(u0), a1);
                a0 = fmaf(w1v, lo_bf(u1), a0);
                a1 = fmaf(w1v, hi_bf(u1), a1);
            } else {
                float h0 = b2f_s(hwu[(size_t)s0 * F + lane]);
                float h1 = b2f_s(hwu[(size_t)s1 * F + lane]);
                a0 = fmaf(w0, h0, a0);
                a0 = fmaf(w1v, h1, a0);
            }
        }
        if (j < cnt) {
            int s0 = __shfl(s, j);
            float w0 = __shfl(w, j);
            if (FPL == 2) {
                unsigned u0 = *(const unsigned*)(hwu + (size_t)s0 * F + 2 * lane);
                a0 = fmaf(w0, lo_bf(u0), a0);
                a1 = fmaf(w0, hi_bf(u0), a1);
            } else {
                a0 = fmaf(w0, b2f_s(hwu[(size_t)s0 * F + lane]), a0);
            }
        }
    }
#pragma unroll
    for (int off = 32; off > 0; off >>= 1) den_l += __shfl_xor(den_l, off);
    float inv = 1.f / (den_l + wself);
    if (FPL == 2) {
        float v0 = fmaxf(a0 * inv + bias[2 * lane], 0.f);
        float v1 = fmaxf(a1 * inv + bias[2 * lane + 1], 0.f);
        unsigned* op = (unsigned*)(out + (size_t)node * ldc + coff);
        op[lane] = pack_bf(v0, v1);
    } else {
        out[(size_t)node * ldc + coff + lane] =
            __float2bfloat16(fmaxf(a0 * inv + bias[lane], 0.f));
    }
}

// ---------------------------------------------------------------------------
// CSR build: count (atomic) -> 3-phase parallel scan -> fill (atomic).
// ---------------------------------------------------------------------------
__global__ void count_kernel(const int* __restrict__ dst, int* __restrict__ cnt,
                             int e)
{
    for (int i = blockIdx.x * blockDim.x + threadIdx.x; i < e;
         i += gridDim.x * blockDim.x)
        atomicAdd(cnt + dst[i], 1);
}

#define SCAN_BLOCKS 256

__global__ __launch_bounds__(256) void scan_local_kernel(
    const int* __restrict__ cnt, int* __restrict__ rowptr,
    int* __restrict__ bsum, int n, int chunk)
{
    __shared__ int tmp[256];
    int b = blockIdx.x, tid = threadIdx.x;
    int i = b * chunk + tid;
    int v = (tid < chunk && i < n) ? cnt[i] : 0;
    tmp[tid] = v;
    __syncthreads();
    for (int off = 1; off < 256; off <<= 1) {
        int t = (tid >= off) ? tmp[tid - off] : 0;
        __syncthreads();
        tmp[tid] += t;
        __syncthreads();
    }
    if (tid < chunk && i < n) rowptr[i] = tmp[tid] - v;
    if (tid == 255) bsum[b] = tmp[255];
}

__global__ __launch_bounds__(256) void scan_bsums_kernel(
    int* __restrict__ bsum, int* __restrict__ rowptr, int n)
{
    __shared__ int tmp[256];
    int tid = threadIdx.x;
    int v = bsum[tid];
    tmp[tid] = v;
    __syncthreads();
    for (int off = 1; off < 256; off <<= 1) {
        int t = (tid >= off) ? tmp[tid - off] : 0;
        __syncthreads();
        tmp[tid] += t;
        __syncthreads();
    }
    bsum[tid] = tmp[tid] - v;
    if (tid == 255) rowptr[n] = tmp[255];
}

__global__ __launch_bounds__(256) void scan_add_kernel(
    int* __restrict__ rowptr, int* __restrict__ nextp,
    const int* __restrict__ bsum, int n, int chunk)
{
    int b = blockIdx.x, tid = threadIdx.x;
    int i = b * chunk + tid;
    if (tid < chunk && i < n) {
        int v = rowptr[i] + bsum[b];
        rowptr[i] = v;
        nextp[i] = v;
    }
}

__global__ void fill_kernel(const int* __restrict__ src,
                            const int* __restrict__ dst,
                            int* __restrict__ nextp, int* __restrict__ colidx,
                            int e)
{
    for (int i = blockIdx.x * blockDim.x + threadIdx.x; i < e;
         i += gridDim.x * blockDim.x) {
        int pos = atomicAdd(nextp + dst[i], 1);
        colidx[pos] = src[i];
    }
}

// ---------------------------------------------------------------------------
extern "C" void kernel_launch(void* const* d_in, const int* in_sizes, int n_in,
                              void* d_out, int out_size, void* d_ws,
                              size_t ws_size, hipStream_t stream)
{
    const int N = N_NODES;
    const int E = N_EDGES;

    const float* x_all = (const float*)d_in[0];
    const int* edges = (const int*)d_in[1];
    const int* e_src = edges;
    const int* e_dst = edges + E;

    const float* sep1_w = (const float*)d_in[2];  const float* sep1_b = (const float*)d_in[3];
    const float* sep2_w = (const float*)d_in[4];  const float* sep2_b = (const float*)d_in[5];
    const float* sep3_w = (const float*)d_in[6];  const float* sep3_b = (const float*)d_in[7];
    const float* sep4_w = (const float*)d_in[8];  const float* sep4_b = (const float*)d_in[9];
    const float* sep5_w = (const float*)d_in[10]; const float* sep5_b = (const float*)d_in[11];
    const float* sep6_w = (const float*)d_in[12]; const float* sep6_b = (const float*)d_in[13];
    const float* sep7_w = (const float*)d_in[14]; const float* sep7_b = (const float*)d_in[15];
    const float* sep8_w = (const float*)d_in[16]; const float* sep8_b = (const float*)d_in[17];
    const float* conv1_w = (const float*)d_in[18];
    const float* conv1_as = (const float*)d_in[19];
    const float* conv1_ad = (const float*)d_in[20];
    const float* conv1_b = (const float*)d_in[21];
    const float* conv2_w = (const float*)d_in[22];
    const float* conv2_as = (const float*)d_in[23];
    const float* conv2_ad = (const float*)d_in[24];
    const float* conv2_b = (const float*)d_in[25];
    const float* conv3_w = (const float*)d_in[26];
    const float* conv3_as = (const float*)d_in[27];
    const float* conv3_ad = (const float*)d_in[28];
    const float* conv3_b = (const float*)d_in[29];
    const float* lstm_wih = (const float*)d_in[30];
    const float* lstm_bih = (const float*)d_in[32];
    const float* lstm_bhh = (const float*)d_in[33];
    const float* lin1_w = (const float*)d_in[34]; const float* lin1_b = (const float*)d_in[35];
    const float* lin2_w = (const float*)d_in[36]; const float* lin2_b = (const float*)d_in[37];
    const float* lin3_w = (const float*)d_in[38]; const float* lin3_b = (const float*)d_in[39];

    char* ws = (char*)d_ws;
    size_t off = 0;
    auto alloc = [&](size_t bytes) {
        void* p = ws + off;
        off += (bytes + 255) & ~(size_t)255;
        return p;
    };
    short* x0 = (short*)alloc((size_t)NP * 384 * 2);  // reused for C / xg
    short* Bb = (short*)alloc((size_t)NP * 128 * 2);  // hw buffer
    float* ssrc = (float*)alloc((size_t)N * 4);
    float* sdst = (float*)alloc((size_t)N * 4);
    int* rowptr = (int*)alloc((size_t)(N + 1) * 4);
    int* nextp  = (int*)alloc((size_t)N * 4);
    int* cnt    = (int*)alloc((size_t)N * 4);
    int* bsum   = (int*)alloc((size_t)SCAN_BLOCKS * 4);
    int* colidx = (int*)alloc((size_t)E * 4);

    // packed weights (always fit)
    short* conv1p = (short*)alloc((size_t)128 * 384 * 2);
    short* conv2p = (short*)alloc((size_t)128 * 128 * 2);
    short* conv3p = (short*)alloc((size_t)64 * 128 * 2);
    short* sep1p  = (short*)alloc((size_t)64 * 32 * 2);
    short* sep2p  = (short*)alloc((size_t)64 * 32 * 2);
    short* sep3p  = (short*)alloc((size_t)128 * 64 * 2);
    short* sep4p  = (short*)alloc((size_t)128 * 384 * 2);
    short* sep5p  = (short*)alloc((size_t)64 * 64 * 2);
    short* sep6p  = (short*)alloc((size_t)64 * 64 * 2);
    short* sep7p  = (short*)alloc((size_t)128 * 128 * 2);
    short* sep8p  = (short*)alloc((size_t)128 * 128 * 2);
    short* lin1p  = (short*)alloc((size_t)64 * 128 * 2);
    short* lin2p  = (short*)alloc((size_t)64 * 64 * 2);
    short* lin3p  = (short*)alloc((size_t)64 * 64 * 2);

    // packed x_all slices for branches 3/4 (guarded by ws budget)
    size_t need_xs = off + (size_t)NP * 64 * 2 + (size_t)NP * 384 * 2 + 1024;
    bool packx = ws_size >= need_xs;
    short* xs3 = packx ? (short*)alloc((size_t)NP * 64 * 2) : nullptr;
    short* xs4 = packx ? (short*)alloc((size_t)NP * 384 * 2) : nullptr;

    short* C  = x0;  // GAT ping buffer (N,128); x0 dead after conv1 gemm
    bf16* xg = (bf16*)x0;  // GAT3 out (N,64); C dead after conv3 gemm

    dim3 blk(256);
    int gx = NP / 64;  // 782
    int nb4 = (N + 3) / 4;
    int chunk = (N + SCAN_BLOCKS - 1) / SCAN_BLOCKS;

    // --- CSR build ---
    hipMemsetAsync(cnt, 0, (size_t)N * 4, stream);
    count_kernel<<<1024, 256, 0, stream>>>(e_dst, cnt, E);
    scan_local_kernel<<<SCAN_BLOCKS, 256, 0, stream>>>(cnt, rowptr, bsum, N, chunk);
    scan_bsums_kernel<<<1, 256, 0, stream>>>(bsum, rowptr, N);
    scan_add_kernel<<<SCAN_BLOCKS, 256, 0, stream>>>(rowptr, nextp, bsum, N, chunk);
    fill_kernel<<<1024, 256, 0, stream>>>(e_src, e_dst, nextp, colidx, E);

    // --- pack weights (+ x slices) to bf16 ---
    {
        PackArgs pa{};
        unsigned long long total = 0;
        int np = 0;
        auto addp = [&](const float* src, short* dst, int lda, int M, int K,
                        int Mp, int Kp) {
            pa.d[np].src = src; pa.d[np].dst = dst; pa.d[np].lda = lda;
            pa.d[np].M = M; pa.d[np].K = K; pa.d[np].Mp = Mp; pa.d[np].Kp = Kp;
            pa.sz[np] = (unsigned long long)Mp * Kp;
            total += pa.sz[np];
            np++;
        };
        if (packx) {
            addp(x_all + 56, xs4, 441, N, 365, NP, 384);
            addp(x_all + 16, xs3, 441, N, 40, NP, 64);
        }
        addp(conv1_w, conv1p, 384, 128, 384, 128, 384);
        addp(sep4_w, sep4p, 365, 128, 365, 128, 384);
        addp(conv2_w, conv2p, 128, 128, 128, 128, 128);
        addp(sep7_w, sep7p, 128, 128, 128, 128, 128);
        addp(sep8_w, sep8p, 128, 128, 128, 128, 128);
        addp(conv3_w, conv3p, 128, 64, 128, 64, 128);
        addp(lin1_w, lin1p, 128, 64, 128, 64, 128);
        addp(sep3_w, sep3p, 40, 128, 40, 128, 64);
        addp(sep5_w, sep5p, 64, 64, 64, 64, 64);
        addp(sep6_w, sep6p, 64, 64, 64, 64, 64);
        addp(lin2_w, lin2p, 64, 64, 64, 64, 64);
        addp(lin3_w, lin3p, 64, 56, 64, 64, 64);
        addp(sep1_w, sep1p, 2, 64, 2, 64, 32);
        addp(sep2_w, sep2p, 13, 64, 13, 64, 32);
        pa.n = np;
        pack_all_kernel<<<2048, 256, 0, stream>>>(pa, total);
    }

    // --- four fused MLP branches -> x0 (N,384) bf16 ---
    brmlp_kernel<0, 4, 4, 1><<<gx, blk, 0, stream>>>(
        x_all, 441, 1, sep1p, sep1_b, sep5p, sep5_b, (bf16*)x0, 384, 0, N, 2);
    brmlp_kernel<0, 4, 4, 1><<<gx, blk, 0, stream>>>(
        x_all, 441, 3, sep2p, sep2_b, sep6p, sep6_b, (bf16*)x0, 384, 64, N, 13);
    if (packx) {
        brmlp_kernel<1, 8, 8, 2><<<gx, blk, 0, stream>>>(
            xs3, 64, 0, sep3p, sep3_b, sep7p, sep7_b, (bf16*)x0, 384, 128, N, 64);
        brmlp_kernel<1, 8, 8, 12><<<gx, blk, 0, stream>>>(
            xs4, 384, 0, sep4p, sep4_b, sep8p, sep8_b, (bf16*)x0, 384, 256, N, 384);
    } else {
        brmlp_kernel<0, 8, 8, 2><<<gx, blk, 0, stream>>>(
            x_all, 441, 16, sep3p, sep3_b, sep7p, sep7_b, (bf16*)x0, 384, 128, N, 40);
        brmlp_kernel<0, 8, 8, 12><<<gx, blk, 0, stream>>>(
            x_all, 441, 56, sep4p, sep4_b, sep8p, sep8_b, (bf16*)x0, 384, 256, N, 365);
    }

    // --- GAT layers (scores fused into GEMM epilogue; direct-load GEMM) ---
    dgemm_kernel<0, 1, 8, 12, 1><<<gx, blk, 0, stream>>>(
        x0, 384, conv1p, nullptr, Bb, 128, 0, N, 128,
        conv1_as, conv1_ad, ssrc, sdst);
    gat_fused_kernel<2><<<nb4, 256, 0, stream>>>(
        (const bf16*)Bb, rowptr, colidx, ssrc, sdst, conv1_b, (bf16*)C, 128, 0, N, 128);

    dgemm_kernel<0, 1, 8, 4, 1><<<gx, blk, 0, stream>>>(
        C, 128, conv2p, nullptr, Bb, 128, 0, N, 128,
        conv2_as, conv2_ad, ssrc, sdst);
    gat_fused_kernel<2><<<nb4, 256, 0, stream>>>(
        (const bf16*)Bb, rowptr, colidx, ssrc, sdst, conv2_b, (bf16*)C, 128, 0, N, 128);

    dgemm_kernel<0, 1, 4, 4, 1><<<gx, blk, 0, stream>>>(
        C, 128, conv3p, nullptr, Bb, 64, 0, N, 64,
        conv3_as, conv3_ad, ssrc, sdst);
    gat_fused_kernel<1><<<nb4, 256, 0, stream>>>(
        (const bf16*)Bb, rowptr, colidx, ssrc, sdst, conv3_b, xg, 64, 0, N, 64);

    // --- fused head: lstm + lin1 + lin2 + lin3 ---
    head_kernel<<<gx, blk, 0, stream>>>(
        xg, x_all, lstm_wih, lstm_bih, lstm_bhh,
        lin1p, lin1_b, lin2p, lin2_b, lin3p, lin3_b,
        (float*)d_out, N);
}

// Round 7
// 726.242 us; speedup vs baseline: 2.3858x; 1.0461x over previous
//
#include <hip/hip_runtime.h>
#include <hip/hip_bf16.h>
#include <math.h>

#define N_NODES 50000
#define N_EDGES 800000
#define NP 50048  // N rounded up to 64

typedef __hip_bfloat16 bf16;
typedef __attribute__((ext_vector_type(8))) short short8;
typedef __attribute__((ext_vector_type(4))) float f32x4;

__device__ __forceinline__ float lrelu(float x) { return x > 0.f ? x : 0.2f * x; }

__device__ __forceinline__ short f2b(float v) {
    bf16 h = __float2bfloat16(v);
    return *reinterpret_cast<short*>(&h);
}
__device__ __forceinline__ float lo_bf(unsigned u) { return __uint_as_float(u << 16); }
__device__ __forceinline__ float hi_bf(unsigned u) { return __uint_as_float(u & 0xFFFF0000u); }
__device__ __forceinline__ float b2f_s(unsigned short s) {
    return __uint_as_float(((unsigned)s) << 16);
}
__device__ __forceinline__ unsigned pack_bf(float v0, float v1) {
    unsigned a = (unsigned)(unsigned short)f2b(v0);
    unsigned b = (unsigned)(unsigned short)f2b(v1);
    return a | (b << 16);
}
__device__ __forceinline__ float sigm(float x) { return 1.f / (1.f + expf(-x)); }

// ---------------------------------------------------------------------------
// Fast x_all slice packer: CPR = chunks (of 8 elems) per padded row (Kp/8),
// K = valid cols, OFF = column offset in x_all (lda 441). One thread = one
// 8-elem chunk: 8 coalesced dword loads -> one 16B short8 store.
// ---------------------------------------------------------------------------
template <int CPR, int K, int OFF>
__global__ __launch_bounds__(256) void pack_x_kernel(
    const float* __restrict__ x, short* __restrict__ out, int nrows)
{
    int chunk = blockIdx.x * 256 + threadIdx.x;
    int r = chunk / CPR;               // compile-time divisor
    int c8 = (chunk - r * CPR) * 8;
    if (r >= NP) return;
    short8 tmp;
    if (r < nrows) {
        const float* p = x + (size_t)r * 441 + OFF + c8;
#pragma unroll
        for (int j = 0; j < 8; j++) {
            int k = c8 + j;
            tmp[j] = (k < K) ? f2b(p[j]) : (short)0;
        }
    } else {
#pragma unroll
        for (int j = 0; j < 8; j++) tmp[j] = 0;
    }
    *(short8*)(out + (size_t)r * (CPR * 8) + c8) = tmp;
}

// ---------------------------------------------------------------------------
// Batched f32 -> bf16 packer for the (small) weight tensors.
// ---------------------------------------------------------------------------
struct PackDesc {
    const float* src;
    short* dst;
    int lda, M, K, Mp, Kp;
};
struct PackArgs {
    PackDesc d[16];
    unsigned long long sz[16];
    int n;
};

__global__ __launch_bounds__(256) void pack_all_kernel(PackArgs pa,
                                                       unsigned long long total)
{
    for (unsigned long long i =
             (unsigned long long)blockIdx.x * blockDim.x + threadIdx.x;
         i < total; i += (unsigned long long)gridDim.x * blockDim.x) {
        unsigned long long off = i;
        int s = 0;
        while (s < pa.n - 1 && off >= pa.sz[s]) { off -= pa.sz[s]; s++; }
        PackDesc D = pa.d[s];
        int r = (int)(off / (unsigned)D.Kp);
        int k = (int)(off % (unsigned)D.Kp);
        float v = (r < D.M && k < D.K) ? D.src[(size_t)r * D.lda + k] : 0.f;
        D.dst[(size_t)r * D.Kp + k] = f2b(v);
    }
}

// ---------------------------------------------------------------------------
// Direct-from-global MFMA GEMM: 64 rows x CT*16 cols per block, no LDS.
// ---------------------------------------------------------------------------
template <int ACT, int ODT, int CT, int KI, int SCORES>
__global__ __launch_bounds__(256) void dgemm_kernel(
    const short* __restrict__ A, int lda,
    const short* __restrict__ W,
    const float* __restrict__ bias,
    void* __restrict__ Cv, int ldc, int coff, int nrows, int M,
    const float* __restrict__ a_src, const float* __restrict__ a_dst,
    float* __restrict__ ssrc, float* __restrict__ sdst)
{
    constexpr int LDW = KI * 32;
    int tid = threadIdx.x;
    int row0 = blockIdx.x * 64;
    int wv = tid >> 6, lane = tid & 63;
    int lrow = lane & 15, quad = lane >> 4;

    const short* Ap = A + (size_t)(row0 + wv * 16 + lrow) * lda + quad * 8;
    const short* Wp = W + (size_t)lrow * LDW + quad * 8;

    f32x4 acc[CT];
#pragma unroll
    for (int ct = 0; ct < CT; ct++)
#pragma unroll
        for (int i = 0; i < 4; i++) acc[ct][i] = 0.f;

#pragma unroll 4
    for (int ki = 0; ki < KI; ki++) {
        short8 a = *(const short8*)(Ap + ki * 32);
#pragma unroll
        for (int ct = 0; ct < CT; ct++) {
            short8 b = *(const short8*)(Wp + (size_t)ct * 16 * LDW + ki * 32);
            acc[ct] = __builtin_amdgcn_mfma_f32_16x16x32_bf16(a, b, acc[ct], 0, 0, 0);
        }
    }

    float* Cf = (float*)Cv;
    bf16*  Cb = (bf16*)Cv;
#pragma unroll
    for (int ct = 0; ct < CT; ct++) {
        int gcol = ct * 16 + lrow;
        if (gcol >= M) continue;
        float bv = bias ? bias[gcol] : 0.f;
#pragma unroll
        for (int i = 0; i < 4; i++) {
            int grow = row0 + wv * 16 + quad * 4 + i;
            if (grow >= nrows) continue;
            float v = acc[ct][i] + bv;
            if (ACT == 1) v = fmaxf(v, 0.f);
            if (ACT == 2) v = sigm(v);
            if (ODT == 1) Cb[(size_t)grow * ldc + coff + gcol] = __float2bfloat16(v);
            else          Cf[(size_t)grow * ldc + coff + gcol] = v;
        }
    }

    if (SCORES) {
        float as_c[CT], ad_c[CT];
#pragma unroll
        for (int ct = 0; ct < CT; ct++) {
            int gcol = ct * 16 + lrow;
            as_c[ct] = (gcol < M) ? a_src[gcol] : 0.f;
            ad_c[ct] = (gcol < M) ? a_dst[gcol] : 0.f;
        }
#pragma unroll
        for (int i = 0; i < 4; i++) {
            float ps = 0.f, pd = 0.f;
#pragma unroll
            for (int ct = 0; ct < CT; ct++) {
                ps = fmaf(acc[ct][i], as_c[ct], ps);
                pd = fmaf(acc[ct][i], ad_c[ct], pd);
            }
#pragma unroll
            for (int off = 8; off > 0; off >>= 1) {
                ps += __shfl_down(ps, off);
                pd += __shfl_down(pd, off);
            }
            if (lrow == 0) {
                int grow = row0 + wv * 16 + quad * 4 + i;
                if (grow < nrows) { ssrc[grow] = ps; sdst[grow] = pd; }
            }
        }
    }
}

// ---------------------------------------------------------------------------
// Fused 2-layer MLP branch: out = relu(W2 @ sig(W1 @ a + b1) + b2), bf16 out.
// ---------------------------------------------------------------------------
template <int ADT, int CT1, int CT2, int KI1>
__global__ __launch_bounds__(256) void brmlp_kernel(
    const void* __restrict__ Av, int lda, int aoff,
    const short* __restrict__ W1p, const float* __restrict__ B1,
    const short* __restrict__ W2p, const float* __restrict__ B2,
    bf16* __restrict__ out, int ldc, int coff, int nrows, int K1)
{
    constexpr int M1 = CT1 * 16;
    constexpr int LDH = M1 + 8;
    constexpr int LDW1 = KI1 * 32;
    __shared__ short sH[64][LDH];

    int tid = threadIdx.x;
    int row0 = blockIdx.x * 64;
    int wv = tid >> 6, lane = tid & 63;
    int lrow = lane & 15, quad = lane >> 4;
    int arow = row0 + wv * 16 + lrow;

    // ---- phase 1 ----
    {
        f32x4 acc[CT1];
#pragma unroll
        for (int ct = 0; ct < CT1; ct++)
#pragma unroll
            for (int i = 0; i < 4; i++) acc[ct][i] = 0.f;

#pragma unroll
        for (int ki = 0; ki < KI1; ki++) {
            short8 a;
            if (ADT == 1) {
                a = *(const short8*)((const short*)Av + (size_t)arow * lda +
                                     ki * 32 + quad * 8);
            } else {
                const float* Af = (const float*)Av;
                bool rok = arow < nrows;
#pragma unroll
                for (int j = 0; j < 8; j++) {
                    int k = ki * 32 + quad * 8 + j;
                    a[j] = (rok && k < K1)
                               ? f2b(Af[(size_t)arow * lda + aoff + k])
                               : (short)0;
                }
            }
#pragma unroll
            for (int ct = 0; ct < CT1; ct++) {
                short8 b = *(const short8*)(W1p + (size_t)(ct * 16 + lrow) * LDW1 +
                                            ki * 32 + quad * 8);
                acc[ct] = __builtin_amdgcn_mfma_f32_16x16x32_bf16(a, b, acc[ct], 0, 0, 0);
            }
        }
#pragma unroll
        for (int ct = 0; ct < CT1; ct++) {
            int col = ct * 16 + lrow;
            float bv = B1[col];
#pragma unroll
            for (int i = 0; i < 4; i++)
                sH[wv * 16 + quad * 4 + i][col] = f2b(sigm(acc[ct][i] + bv));
        }
    }

    // ---- phase 2 (K2 = M1) ----
    {
        f32x4 acc[CT2];
#pragma unroll
        for (int ct = 0; ct < CT2; ct++)
#pragma unroll
            for (int i = 0; i < 4; i++) acc[ct][i] = 0.f;

#pragma unroll
        for (int ki = 0; ki < M1 / 32; ki++) {
            short8 a = *(short8*)&sH[wv * 16 + lrow][ki * 32 + quad * 8];
#pragma unroll
            for (int ct = 0; ct < CT2; ct++) {
                short8 b = *(const short8*)(W2p + (size_t)(ct * 16 + lrow) * M1 +
                                            ki * 32 + quad * 8);
                acc[ct] = __builtin_amdgcn_mfma_f32_16x16x32_bf16(a, b, acc[ct], 0, 0, 0);
            }
        }
#pragma unroll
        for (int ct = 0; ct < CT2; ct++) {
            int gcol = ct * 16 + lrow;
            float bv = B2[gcol];
#pragma unroll
            for (int i = 0; i < 4; i++) {
                int grow = row0 + wv * 16 + quad * 4 + i;
                if (grow >= nrows) continue;
                float v = fmaxf(acc[ct][i] + bv, 0.f);
                out[(size_t)grow * ldc + coff + gcol] = __float2bfloat16(v);
            }
        }
    }
}

// ---------------------------------------------------------------------------
// Fused head: concat(gat3_out, lstm_h) -> lin1(relu) -> lin2(relu) -> lin3.
// ---------------------------------------------------------------------------
__global__ __launch_bounds__(256) void head_kernel(
    const bf16* __restrict__ xg, const float* __restrict__ x_all,
    const float* __restrict__ wih, const float* __restrict__ bih,
    const float* __restrict__ bhh,
    const short* __restrict__ w1p, const float* __restrict__ b1,
    const short* __restrict__ w2p, const float* __restrict__ b2,
    const short* __restrict__ w3p, const float* __restrict__ b3,
    float* __restrict__ dout, int n)
{
    __shared__ short sW[20][200];  // lstm wT[k][gate*64+j], gates i,g,o
    __shared__ float sT[64][20];
    __shared__ short sX[64][136];  // concat row
    __shared__ short sH2[64][72];
    __shared__ short sH3[64][72];

    int tid = threadIdx.x;
    int row0 = blockIdx.x * 64;
    int wv = tid >> 6, lane = tid & 63;
    int lrow = lane & 15, quad = lane >> 4;

    for (int i = tid; i < 20 * 192; i += 256) {
        int k = i / 192, j = i % 192;
        int gate = j >> 6, jj = j & 63;
        int srow = (gate == 0) ? jj : (gate == 1 ? 128 + jj : 192 + jj);
        sW[k][j] = f2b(wih[srow * 20 + k]);
    }
    for (int i = tid; i < 64 * 20; i += 256) {
        int r = i / 20, k = i % 20;
        int grow = row0 + r;
        sT[r][k] = (grow < n) ? x_all[(size_t)grow * 441 + 421 + k] : 0.f;
    }
    for (int i = tid; i < 64 * 8; i += 256) {
        int r = i >> 3, c8 = (i & 7) * 8;
        int grow = row0 + r;
        short8 tmp;
        if (grow < n) {
            tmp = *(const short8*)(((const short*)xg) + (size_t)grow * 64 + c8);
        } else {
#pragma unroll
            for (int j = 0; j < 8; j++) tmp[j] = 0;
        }
        *(short8*)&sX[r][c8] = tmp;
    }
    __syncthreads();

    for (int p = 0; p < 16; p++) {
        int idx = p * 256 + tid;
        int r = idx >> 6, j = idx & 63;
        float gi = 0.f, gg = 0.f, go = 0.f;
#pragma unroll
        for (int k = 0; k < 20; k++) {
            float t = sT[r][k];
            gi = fmaf(t, b2f_s((unsigned short)sW[k][j]), gi);
            gg = fmaf(t, b2f_s((unsigned short)sW[k][64 + j]), gg);
            go = fmaf(t, b2f_s((unsigned short)sW[k][128 + j]), go);
        }
        gi += bih[j] + bhh[j];
        gg += bih[128 + j] + bhh[128 + j];
        go += bih[192 + j] + bhh[192 + j];
        float c = sigm(gi) * tanhf(gg);
        float h = sigm(go) * tanhf(c);
        sX[r][64 + j] = f2b(h);
    }
    __syncthreads();

    f32x4 acc[4];
    // ---- lin1: 128 -> 64, relu ----
#pragma unroll
    for (int ct = 0; ct < 4; ct++)
#pragma unroll
        for (int i = 0; i < 4; i++) acc[ct][i] = 0.f;
#pragma unroll
    for (int ki = 0; ki < 4; ki++) {
        short8 a = *(short8*)&sX[wv * 16 + lrow][ki * 32 + quad * 8];
#pragma unroll
        for (int ct = 0; ct < 4; ct++) {
            short8 b = *(const short8*)(w1p + (size_t)(ct * 16 + lrow) * 128 +
                                        ki * 32 + quad * 8);
            acc[ct] = __builtin_amdgcn_mfma_f32_16x16x32_bf16(a, b, acc[ct], 0, 0, 0);
        }
    }
#pragma unroll
    for (int ct = 0; ct < 4; ct++) {
        int col = ct * 16 + lrow;
        float bv = b1[col];
#pragma unroll
        for (int i = 0; i < 4; i++)
            sH2[wv * 16 + quad * 4 + i][col] = f2b(fmaxf(acc[ct][i] + bv, 0.f));
    }

    // ---- lin2: 64 -> 64, relu (per-wave rows; no barrier needed) ----
#pragma unroll
    for (int ct = 0; ct < 4; ct++)
#pragma unroll
        for (int i = 0; i < 4; i++) acc[ct][i] = 0.f;
#pragma unroll
    for (int ki = 0; ki < 2; ki++) {
        short8 a = *(short8*)&sH2[wv * 16 + lrow][ki * 32 + quad * 8];
#pragma unroll
        for (int ct = 0; ct < 4; ct++) {
            short8 b = *(const short8*)(w2p + (size_t)(ct * 16 + lrow) * 64 +
                                        ki * 32 + quad * 8);
            acc[ct] = __builtin_amdgcn_mfma_f32_16x16x32_bf16(a, b, acc[ct], 0, 0, 0);
        }
    }
#pragma unroll
    for (int ct = 0; ct < 4; ct++) {
        int col = ct * 16 + lrow;
        float bv = b2[col];
#pragma unroll
        for (int i = 0; i < 4; i++)
            sH3[wv * 16 + quad * 4 + i][col] = f2b(fmaxf(acc[ct][i] + bv, 0.f));
    }

    // ---- lin3: 64 -> 56 ----
#pragma unroll
    for (int ct = 0; ct < 4; ct++)
#pragma unroll
        for (int i = 0; i < 4; i++) acc[ct][i] = 0.f;
#pragma unroll
    for (int ki = 0; ki < 2; ki++) {
        short8 a = *(short8*)&sH3[wv * 16 + lrow][ki * 32 + quad * 8];
#pragma unroll
        for (int ct = 0; ct < 4; ct++) {
            short8 b = *(const short8*)(w3p + (size_t)(ct * 16 + lrow) * 64 +
                                        ki * 32 + quad * 8);
            acc[ct] = __builtin_amdgcn_mfma_f32_16x16x32_bf16(a, b, acc[ct], 0, 0, 0);
        }
    }
#pragma unroll
    for (int ct = 0; ct < 4; ct++) {
        int gcol = ct * 16 + lrow;
        if (gcol >= 56) continue;
        float bv = b3[gcol];
#pragma unroll
        for (int i = 0; i < 4; i++) {
            int grow = row0 + wv * 16 + quad * 4 + i;
            if (grow >= n) continue;
            dout[(size_t)grow * 56 + gcol] = acc[ct][i] + bv;
        }
    }
}

// ---------------------------------------------------------------------------
// Fused GAT aggregation (single CSR pass; max-shift cancels in softmax).
// ---------------------------------------------------------------------------
template <int FPL>
__global__ __launch_bounds__(256) void gat_fused_kernel(
    const bf16* __restrict__ hw, const int* __restrict__ rowptr,
    const int* __restrict__ colidx, const float* __restrict__ ss,
    const float* __restrict__ sd, const float* __restrict__ bias,
    bf16* __restrict__ out, int ldc, int coff, int n, int F)
{
    int wv = threadIdx.x >> 6, lane = threadIdx.x & 63;
    int node = blockIdx.x * 4 + wv;
    if (node >= n) return;
    const unsigned short* hwu = (const unsigned short*)hw;
    float sdn = sd[node];
    float wself = expf(lrelu(ss[node] + sdn));
    float a0, a1 = 0.f;
    if (FPL == 2) {
        unsigned u = *(const unsigned*)(hwu + (size_t)node * F + 2 * lane);
        a0 = wself * lo_bf(u);
        a1 = wself * hi_bf(u);
    } else {
        a0 = wself * b2f_s(hwu[(size_t)node * F + lane]);
    }
    int e0 = rowptr[node];
    int deg = rowptr[node + 1] - e0;
    float den_l = 0.f;
    for (int c0 = 0; c0 < deg; c0 += 64) {
        int mye = c0 + lane;
        int s = 0;
        float w = 0.f;
        if (mye < deg) {
            s = colidx[e0 + mye];
            w = expf(lrelu(ss[s] + sdn));
        }
        den_l += w;
        int cnt = min(64, deg - c0);
        int j = 0;
        for (; j + 1 < cnt; j += 2) {
            int s0 = __shfl(s, j), s1 = __shfl(s, j + 1);
            float w0 = __shfl(w, j), w1v = __shfl(w, j + 1);
            if (FPL == 2) {
                unsigned u0 = *(const unsigned*)(hwu + (size_t)s0 * F + 2 * lane);
                unsigned u1 = *(const unsigned*)(hwu + (size_t)s1 * F + 2 * lane);
                a0 = fmaf(w0, lo_bf(u0), a0);
                a1 = fmaf(w0, hi_bf(u0), a1);
                a0 = fmaf(w1v, lo_bf(u1), a0);
                a1 = fmaf(w1v, hi_bf(u1), a1);
            } else {
                float h0 = b2f_s(hwu[(size_t)s0 * F + lane]);
                float h1 = b2f_s(hwu[(size_t)s1 * F + lane]);
                a0 = fmaf(w0, h0, a0);
                a0 = fmaf(w1v, h1, a0);
            }
        }
        if (j < cnt) {
            int s0 = __shfl(s, j);
            float w0 = __shfl(w, j);
            if (FPL == 2) {
                unsigned u0 = *(const unsigned*)(hwu + (size_t)s0 * F + 2 * lane);
                a0 = fmaf(w0, lo_bf(u0), a0);
                a1 = fmaf(w0, hi_bf(u0), a1);
            } else {
                a0 = fmaf(w0, b2f_s(hwu[(size_t)s0 * F + lane]), a0);
            }
        }
    }
#pragma unroll
    for (int off = 32; off > 0; off >>= 1) den_l += __shfl_xor(den_l, off);
    float inv = 1.f / (den_l + wself);
    if (FPL == 2) {
        float v0 = fmaxf(a0 * inv + bias[2 * lane], 0.f);
        float v1 = fmaxf(a1 * inv + bias[2 * lane + 1], 0.f);
        unsigned* op = (unsigned*)(out + (size_t)node * ldc + coff);
        op[lane] = pack_bf(v0, v1);
    } else {
        out[(size_t)node * ldc + coff + lane] =
            __float2bfloat16(fmaxf(a0 * inv + bias[lane], 0.f));
    }
}

// ---------------------------------------------------------------------------
// CSR build: count (atomic) -> 3-phase parallel scan -> fill (atomic).
// ---------------------------------------------------------------------------
__global__ void count_kernel(const int* __restrict__ dst, int* __restrict__ cnt,
                             int e)
{
    for (int i = blockIdx.x * blockDim.x + threadIdx.x; i < e;
         i += gridDim.x * blockDim.x)
        atomicAdd(cnt + dst[i], 1);
}

#define SCAN_BLOCKS 256

__global__ __launch_bounds__(256) void scan_local_kernel(
    const int* __restrict__ cnt, int* __restrict__ rowptr,
    int* __restrict__ bsum, int n, int chunk)
{
    __shared__ int tmp[256];
    int b = blockIdx.x, tid = threadIdx.x;
    int i = b * chunk + tid;
    int v = (tid < chunk && i < n) ? cnt[i] : 0;
    tmp[tid] = v;
    __syncthreads();
    for (int off = 1; off < 256; off <<= 1) {
        int t = (tid >= off) ? tmp[tid - off] : 0;
        __syncthreads();
        tmp[tid] += t;
        __syncthreads();
    }
    if (tid < chunk && i < n) rowptr[i] = tmp[tid] - v;
    if (tid == 255) bsum[b] = tmp[255];
}

__global__ __launch_bounds__(256) void scan_bsums_kernel(
    int* __restrict__ bsum, int* __restrict__ rowptr, int n)
{
    __shared__ int tmp[256];
    int tid = threadIdx.x;
    int v = bsum[tid];
    tmp[tid] = v;
    __syncthreads();
    for (int off = 1; off < 256; off <<= 1) {
        int t = (tid >= off) ? tmp[tid - off] : 0;
        __syncthreads();
        tmp[tid] += t;
        __syncthreads();
    }
    bsum[tid] = tmp[tid] - v;
    if (tid == 255) rowptr[n] = tmp[255];
}

__global__ __launch_bounds__(256) void scan_add_kernel(
    int* __restrict__ rowptr, int* __restrict__ nextp,
    const int* __restrict__ bsum, int n, int chunk)
{
    int b = blockIdx.x, tid = threadIdx.x;
    int i = b * chunk + tid;
    if (tid < chunk && i < n) {
        int v = rowptr[i] + bsum[b];
        rowptr[i] = v;
        nextp[i] = v;
    }
}

__global__ void fill_kernel(const int* __restrict__ src,
                            const int* __restrict__ dst,
                            int* __restrict__ nextp, int* __restrict__ colidx,
                            int e)
{
    for (int i = blockIdx.x * blockDim.x + threadIdx.x; i < e;
         i += gridDim.x * blockDim.x) {
        int pos = atomicAdd(nextp + dst[i], 1);
        colidx[pos] = src[i];
    }
}

// ---------------------------------------------------------------------------
extern "C" void kernel_launch(void* const* d_in, const int* in_sizes, int n_in,
                              void* d_out, int out_size, void* d_ws,
                              size_t ws_size, hipStream_t stream)
{
    const int N = N_NODES;
    const int E = N_EDGES;

    const float* x_all = (const float*)d_in[0];
    const int* edges = (const int*)d_in[1];
    const int* e_src = edges;
    const int* e_dst = edges + E;

    const float* sep1_w = (const float*)d_in[2];  const float* sep1_b = (const float*)d_in[3];
    const float* sep2_w = (const float*)d_in[4];  const float* sep2_b = (const float*)d_in[5];
    const float* sep3_w = (const float*)d_in[6];  const float* sep3_b = (const float*)d_in[7];
    const float* sep4_w = (const float*)d_in[8];  const float* sep4_b = (const float*)d_in[9];
    const float* sep5_w = (const float*)d_in[10]; const float* sep5_b = (const float*)d_in[11];
    const float* sep6_w = (const float*)d_in[12]; const float* sep6_b = (const float*)d_in[13];
    const float* sep7_w = (const float*)d_in[14]; const float* sep7_b = (const float*)d_in[15];
    const float* sep8_w = (const float*)d_in[16]; const float* sep8_b = (const float*)d_in[17];
    const float* conv1_w = (const float*)d_in[18];
    const float* conv1_as = (const float*)d_in[19];
    const float* conv1_ad = (const float*)d_in[20];
    const float* conv1_b = (const float*)d_in[21];
    const float* conv2_w = (const float*)d_in[22];
    const float* conv2_as = (const float*)d_in[23];
    const float* conv2_ad = (const float*)d_in[24];
    const float* conv2_b = (const float*)d_in[25];
    const float* conv3_w = (const float*)d_in[26];
    const float* conv3_as = (const float*)d_in[27];
    const float* conv3_ad = (const float*)d_in[28];
    const float* conv3_b = (const float*)d_in[29];
    const float* lstm_wih = (const float*)d_in[30];
    const float* lstm_bih = (const float*)d_in[32];
    const float* lstm_bhh = (const float*)d_in[33];
    const float* lin1_w = (const float*)d_in[34]; const float* lin1_b = (const float*)d_in[35];
    const float* lin2_w = (const float*)d_in[36]; const float* lin2_b = (const float*)d_in[37];
    const float* lin3_w = (const float*)d_in[38]; const float* lin3_b = (const float*)d_in[39];

    char* ws = (char*)d_ws;
    size_t off = 0;
    auto alloc = [&](size_t bytes) {
        void* p = ws + off;
        off += (bytes + 255) & ~(size_t)255;
        return p;
    };
    short* x0 = (short*)alloc((size_t)NP * 384 * 2);  // reused for C / xg
    short* Bb = (short*)alloc((size_t)NP * 128 * 2);  // hw buffer
    float* ssrc = (float*)alloc((size_t)N * 4);
    float* sdst = (float*)alloc((size_t)N * 4);
    int* rowptr = (int*)alloc((size_t)(N + 1) * 4);
    int* nextp  = (int*)alloc((size_t)N * 4);
    int* cnt    = (int*)alloc((size_t)N * 4);
    int* bsum   = (int*)alloc((size_t)SCAN_BLOCKS * 4);
    int* colidx = (int*)alloc((size_t)E * 4);

    // packed weights (always fit)
    short* conv1p = (short*)alloc((size_t)128 * 384 * 2);
    short* conv2p = (short*)alloc((size_t)128 * 128 * 2);
    short* conv3p = (short*)alloc((size_t)64 * 128 * 2);
    short* sep1p  = (short*)alloc((size_t)64 * 32 * 2);
    short* sep2p  = (short*)alloc((size_t)64 * 32 * 2);
    short* sep3p  = (short*)alloc((size_t)128 * 64 * 2);
    short* sep4p  = (short*)alloc((size_t)128 * 384 * 2);
    short* sep5p  = (short*)alloc((size_t)64 * 64 * 2);
    short* sep6p  = (short*)alloc((size_t)64 * 64 * 2);
    short* sep7p  = (short*)alloc((size_t)128 * 128 * 2);
    short* sep8p  = (short*)alloc((size_t)128 * 128 * 2);
    short* lin1p  = (short*)alloc((size_t)64 * 128 * 2);
    short* lin2p  = (short*)alloc((size_t)64 * 64 * 2);
    short* lin3p  = (short*)alloc((size_t)64 * 64 * 2);

    // packed x_all slices for branches 3/4 (guarded by ws budget)
    size_t need_xs = off + (size_t)NP * 64 * 2 + (size_t)NP * 384 * 2 + 1024;
    bool packx = ws_size >= need_xs;
    short* xs3 = packx ? (short*)alloc((size_t)NP * 64 * 2) : nullptr;
    short* xs4 = packx ? (short*)alloc((size_t)NP * 384 * 2) : nullptr;

    short* C  = x0;       // GAT ping buffer (N,128); x0 dead after conv1 gemm
    bf16* xg = (bf16*)x0; // GAT3 out (N,64); C dead after conv3 gemm

    dim3 blk(256);
    int gx = NP / 64;  // 782
    int nb4 = (N + 3) / 4;
    int chunk = (N + SCAN_BLOCKS - 1) / SCAN_BLOCKS;

    // --- CSR build ---
    hipMemsetAsync(cnt, 0, (size_t)N * 4, stream);
    count_kernel<<<1024, 256, 0, stream>>>(e_dst, cnt, E);
    scan_local_kernel<<<SCAN_BLOCKS, 256, 0, stream>>>(cnt, rowptr, bsum, N, chunk);
    scan_bsums_kernel<<<1, 256, 0, stream>>>(bsum, rowptr, N);
    scan_add_kernel<<<SCAN_BLOCKS, 256, 0, stream>>>(rowptr, nextp, bsum, N, chunk);
    fill_kernel<<<1024, 256, 0, stream>>>(e_src, e_dst, nextp, colidx, E);

    // --- pack x slices (fast path) + weights (generic) to bf16 ---
    if (packx) {
        pack_x_kernel<48, 365, 56><<<(NP * 48 + 255) / 256, blk, 0, stream>>>(
            x_all, xs4, N);
        pack_x_kernel<8, 40, 16><<<(NP * 8 + 255) / 256, blk, 0, stream>>>(
            x_all, xs3, N);
    }
    {
        PackArgs pa{};
        unsigned long long total = 0;
        int np = 0;
        auto addp = [&](const float* src, short* dst, int lda, int M, int K,
                        int Mp, int Kp) {
            pa.d[np].src = src; pa.d[np].dst = dst; pa.d[np].lda = lda;
            pa.d[np].M = M; pa.d[np].K = K; pa.d[np].Mp = Mp; pa.d[np].Kp = Kp;
            pa.sz[np] = (unsigned long long)Mp * Kp;
            total += pa.sz[np];
            np++;
        };
        addp(conv1_w, conv1p, 384, 128, 384, 128, 384);
        addp(sep4_w, sep4p, 365, 128, 365, 128, 384);
        addp(conv2_w, conv2p, 128, 128, 128, 128, 128);
        addp(sep7_w, sep7p, 128, 128, 128, 128, 128);
        addp(sep8_w, sep8p, 128, 128, 128, 128, 128);
        addp(conv3_w, conv3p, 128, 64, 128, 64, 128);
        addp(lin1_w, lin1p, 128, 64, 128, 64, 128);
        addp(sep3_w, sep3p, 40, 128, 40, 128, 64);
        addp(sep5_w, sep5p, 64, 64, 64, 64, 64);
        addp(sep6_w, sep6p, 64, 64, 64, 64, 64);
        addp(lin2_w, lin2p, 64, 64, 64, 64, 64);
        addp(lin3_w, lin3p, 64, 56, 64, 64, 64);
        addp(sep1_w, sep1p, 2, 64, 2, 64, 32);
        addp(sep2_w, sep2p, 13, 64, 13, 64, 32);
        pa.n = np;
        pack_all_kernel<<<512, 256, 0, stream>>>(pa, total);
    }

    // --- four fused MLP branches -> x0 (N,384) bf16 ---
    brmlp_kernel<0, 4, 4, 1><<<gx, blk, 0, stream>>>(
        x_all, 441, 1, sep1p, sep1_b, sep5p, sep5_b, (bf16*)x0, 384, 0, N, 2);
    brmlp_kernel<0, 4, 4, 1><<<gx, blk, 0, stream>>>(
        x_all, 441, 3, sep2p, sep2_b, sep6p, sep6_b, (bf16*)x0, 384, 64, N, 13);
    if (packx) {
        brmlp_kernel<1, 8, 8, 2><<<gx, blk, 0, stream>>>(
            xs3, 64, 0, sep3p, sep3_b, sep7p, sep7_b, (bf16*)x0, 384, 128, N, 64);
        brmlp_kernel<1, 8, 8, 12><<<gx, blk, 0, stream>>>(
            xs4, 384, 0, sep4p, sep4_b, sep8p, sep8_b, (bf16*)x0, 384, 256, N, 384);
    } else {
        brmlp_kernel<0, 8, 8, 2><<<gx, blk, 0, stream>>>(
            x_all, 441, 16, sep3p, sep3_b, sep7p, sep7_b, (bf16*)x0, 384, 128, N, 40);
        brmlp_kernel<0, 8, 8, 12><<<gx, blk, 0, stream>>>(
            x_all, 441, 56, sep4p, sep4_b, sep8p, sep8_b, (bf16*)x0, 384, 256, N, 365);
    }

    // --- GAT layers (scores fused into GEMM epilogue; direct-load GEMM) ---
    dgemm_kernel<0, 1, 8, 12, 1><<<gx, blk, 0, stream>>>(
        x0, 384, conv1p, nullptr, Bb, 128, 0, N, 128,
        conv1_as, conv1_ad, ssrc, sdst);
    gat_fused_kernel<2><<<nb4, 256, 0, stream>>>(
        (const bf16*)Bb, rowptr, colidx, ssrc, sdst, conv1_b, (bf16*)C, 128, 0, N, 128);

    dgemm_kernel<0, 1, 8, 4, 1><<<gx, blk, 0, stream>>>(
        C, 128, conv2p, nullptr, Bb, 128, 0, N, 128,
        conv2_as, conv2_ad, ssrc, sdst);
    gat_fused_kernel<2><<<nb4, 256, 0, stream>>>(
        (const bf16*)Bb, rowptr, colidx, ssrc, sdst, conv2_b, (bf16*)C, 128, 0, N, 128);

    dgemm_kernel<0, 1, 4, 4, 1><<<gx, blk, 0, stream>>>(
        C, 128, conv3p, nullptr, Bb, 64, 0, N, 64,
        conv3_as, conv3_ad, ssrc, sdst);
    gat_fused_kernel<1><<<nb4, 256, 0, stream>>>(
        (const bf16*)Bb, rowptr, colidx, ssrc, sdst, conv3_b, xg, 64, 0, N, 64);

    // --- fused head: lstm + lin1 + lin2 + lin3 ---
    head_kernel<<<gx, blk, 0, stream>>>(
        xg, x_all, lstm_wih, lstm_bih, lstm_bhh,
        lin1p, lin1_b, lin2p, lin2_b, lin3p, lin3_b,
        (float*)d_out, N);
}